// Round 10
// baseline (1000.721 us; speedup 1.0000x reference)
//
#include <hip/hip_runtime.h>

typedef short short8 __attribute__((ext_vector_type(8)));
typedef short short4v __attribute__((ext_vector_type(4)));
typedef float f32x4 __attribute__((ext_vector_type(4)));

__device__ inline unsigned short f32_to_bf16_rne(float f) {
  unsigned int u = __float_as_uint(f);
  unsigned int r = (u + 0x7fffu + ((u >> 16) & 1u)) >> 16;
  return (unsigned short)r;
}
__device__ inline float bf16_to_f32(unsigned short h) {
  return __uint_as_float(((unsigned int)h) << 16);
}

// ---------------- workspace layout (float offsets) ----------------
// bf16 qkv: qh/ql -> Q region, kh/kl -> K region, vth/vtl (V^T [d][j]) -> V region
// att (O, fp32) -> ATT.  spart -> SPART; atth/attl (bf16 O natural [bn][i][d])
// at SPART+2M/+3M.  score / idx / cout / y / t1
// aliases: whi/wlo (up-w) -> XD; dwhi/dwlo (down-w) -> SPART (dead before spart use)
//          xbh -> Q..K, xbl -> V..ATT (dead after conv_down)
//          coutT -> t1 region; dpart -> y region
constexpr size_t OFF_XD    = 0;
constexpr size_t OFF_Q     = 2097152;
constexpr size_t OFF_K     = 4194304;
constexpr size_t OFF_V     = 6291456;
constexpr size_t OFF_ATT   = 8388608;
constexpr size_t OFF_SPART = 10485760;
constexpr size_t OFF_SCORE = 14680064;
constexpr size_t OFF_IDX   = 14712832;
constexpr size_t OFF_COUT  = 14721024;
constexpr size_t OFF_Y     = 23109632;
constexpr size_t OFF_T1    = 31498240;
constexpr size_t WS_FLOATS = 39886848;

// ---------------- 0a. x NCHW -> NHWC split-bf16 (xbh/xbl [b][ih][iw][ci]) ------
__global__ __launch_bounds__(256) void k_x2bf(const float* __restrict__ x,
    unsigned short* __restrict__ xbh, unsigned short* __restrict__ xbl) {
  int bid = blockIdx.x;              // b*128 + ih*2 + iwh
  int b = bid >> 7;
  int ih = (bid >> 1) & 63;
  int iwh = bid & 1;
  int t = threadIdx.x;
  __shared__ float ts[256][33];
  for (int it = 0; it < 32; ++it) {
    int idx = it * 256 + t;
    int ci = idx >> 5;
    int iwl = idx & 31;
    ts[ci][iwl] = x[(((size_t)(b * 256 + ci) * 64 + ih) * 64) + iwh * 32 + iwl];
  }
  __syncthreads();
  int iwl = t >> 3;
  int cb = (t & 7) * 32;
  size_t base = (((size_t)(b * 64 + ih) * 64) + iwh * 32 + iwl) * 256 + cb;
#pragma unroll
  for (int j = 0; j < 32; j += 2) {
    float v0 = ts[cb + j][iwl];
    float v1 = ts[cb + j + 1][iwl];
    unsigned short h0 = f32_to_bf16_rne(v0);
    unsigned short h1 = f32_to_bf16_rne(v1);
    unsigned short l0 = f32_to_bf16_rne(v0 - bf16_to_f32(h0));
    unsigned short l1 = f32_to_bf16_rne(v1 - bf16_to_f32(h1));
    *(ushort2*)&xbh[base + j] = make_ushort2(h0, h1);
    *(ushort2*)&xbl[base + j] = make_ushort2(l0, l1);
  }
}

// ---------------- 0b. down_w -> split-bf16 dwhi/dwlo [kk][co][ci] --------------
__global__ __launch_bounds__(256) void k_wt_dnb(const float* __restrict__ w,
    unsigned short* __restrict__ dwhi, unsigned short* __restrict__ dwlo) {
  int idx = blockIdx.x * 256 + threadIdx.x;   // 1,048,576 = (kk*256+co)*256+ci
  int ci = idx & 255;
  int co = (idx >> 8) & 255;
  int kk = idx >> 16;
  float v = w[((size_t)(co * 256 + ci)) * 16 + kk];
  unsigned short h = f32_to_bf16_rne(v);
  unsigned short l = f32_to_bf16_rne(v - bf16_to_f32(h));
  dwhi[idx] = h;
  dwlo[idx] = l;
}

// ---------------- 0c. up_w -> split-bf16 whi/wlo [cls][tap][co][ci] ----------
__global__ __launch_bounds__(256) void k_wt_upb(const float* __restrict__ w,
    unsigned short* __restrict__ whi, unsigned short* __restrict__ wlo) {
  int idx = blockIdx.x * 256 + threadIdx.x;   // 1,048,576
  int ci = idx & 255;
  int co = (idx >> 8) & 255;
  int tp = idx >> 16;                         // 0..15
  int cls = tp >> 2, tap = tp & 3;
  int r = cls >> 1, s = cls & 1;
  int a_ = tap >> 1, b_ = tap & 1;
  int kh = a_ ? (r ? 2 : 3) : (r ? 0 : 1);
  int kw = b_ ? (s ? 2 : 3) : (s ? 0 : 1);
  float v = w[((size_t)(ci * 256 + co)) * 16 + kh * 4 + kw];
  unsigned short h = f32_to_bf16_rne(v);
  unsigned short l = f32_to_bf16_rne(v - bf16_to_f32(h));
  whi[idx] = h;
  wlo[idx] = l;
}

// ---------------- 1. down conv: split-bf16 MFMA implicit GEMM ------------------
__global__ __launch_bounds__(256) void k_conv_down_mfma(
    const unsigned short* __restrict__ xbh, const unsigned short* __restrict__ xbl,
    const unsigned short* __restrict__ dwhi, const unsigned short* __restrict__ dwlo,
    const float* __restrict__ bias, float* __restrict__ part) {
  int blk = blockIdx.x;              // ((ks*8 + b)*4 + ct)*32 + pt
  int pt = blk & 31;
  int ct = (blk >> 5) & 3;
  int b = (blk >> 7) & 7;
  int ks = blk >> 10;
  int oh2 = pt >> 1;                 // 0..15 (pair of oh rows)
  int owh = pt & 1;                  // ow half (16)
  int tid = threadIdx.x;
  int w = tid >> 6;                  // wave 0..3 -> co quarter
  int lane = tid & 63;
  int lq = lane >> 4;
  int lr = lane & 15;
  int co = ct * 64 + w * 16 + lr;

  __shared__ __align__(16) unsigned short AH[6][34][40];
  __shared__ __align__(16) unsigned short AL[6][34][40];

  f32x4 acc[2];
  acc[0] = (f32x4){0.f, 0.f, 0.f, 0.f};
  acc[1] = (f32x4){0.f, 0.f, 0.f, 0.f};

  int ih0 = 4 * oh2 - 1;             // tile row 0
  int iw0 = owh * 32 - 1;            // tile col 0
  const short8 zero8 = {0, 0, 0, 0, 0, 0, 0, 0};

  for (int ch = 0; ch < 2; ++ch) {
    int ci0 = ks * 64 + ch * 32;
    __syncthreads();
    for (int idx = tid; idx < 6 * 34 * 4; idx += 256) {
      int q = idx & 3;
      int cell = idx >> 2;
      int row = cell / 34;
      int col = cell - row * 34;
      int ih = ih0 + row;
      int iw = iw0 + col;
      short8 h = zero8, l = zero8;
      if ((unsigned)ih < 64u && (unsigned)iw < 64u) {
        size_t gg = (((size_t)(b * 64 + ih) * 64) + iw) * 256 + ci0 + q * 8;
        h = *(const short8*)&xbh[gg];
        l = *(const short8*)&xbl[gg];
      }
      *(short8*)&AH[row][col][q * 8] = h;
      *(short8*)&AL[row][col][q * 8] = l;
    }
    __syncthreads();
#pragma unroll
    for (int tap = 0; tap < 16; ++tap) {
      int kh = tap >> 2, kw = tap & 3;
      size_t woff = ((size_t)tap * 256 + co) * 256 + ci0 + 8 * lq;
      short8 bh = *(const short8*)&dwhi[woff];
      short8 bl = *(const short8*)&dwlo[woff];
#pragma unroll
      for (int pf = 0; pf < 2; ++pf) {
        short8 ah = *(const short8*)&AH[2 * pf + kh][2 * lr + kw][8 * lq];
        short8 al = *(const short8*)&AL[2 * pf + kh][2 * lr + kw][8 * lq];
        acc[pf] = __builtin_amdgcn_mfma_f32_16x16x32_bf16(ah, bh, acc[pf], 0, 0, 0);
        acc[pf] = __builtin_amdgcn_mfma_f32_16x16x32_bf16(al, bh, acc[pf], 0, 0, 0);
        acc[pf] = __builtin_amdgcn_mfma_f32_16x16x32_bf16(ah, bl, acc[pf], 0, 0, 0);
      }
    }
  }

  float bv = (ks == 0) ? bias[co] : 0.f;
  int bn = b * 4 + ct;
  int d = w * 16 + lr;
  float* pb = part + (size_t)ks * 2097152;
#pragma unroll
  for (int pf = 0; pf < 2; ++pf) {
    int oh = 2 * oh2 + pf;
#pragma unroll
    for (int reg = 0; reg < 4; ++reg) {
      int ow = owh * 16 + lq * 4 + reg;
      int pix = oh * 32 + ow;
      pb[((size_t)bn * 1024 + pix) * 64 + d] = acc[pf][reg] + bv;
    }
  }
}

// ---------------- 2. QKV coarse v2: 64-row tile, waves = (q,k,v), coalesced ----
__global__ __launch_bounds__(192) void k_qkv_coarse(const float* __restrict__ part,
    const float* __restrict__ W, const float* __restrict__ bias,
    unsigned short* __restrict__ qh, unsigned short* __restrict__ ql,
    unsigned short* __restrict__ kh, unsigned short* __restrict__ kl,
    unsigned short* __restrict__ vth, unsigned short* __restrict__ vtl) {
  int blk = blockIdx.x;
  int bn = blk >> 4;
  int i0 = (blk & 15) * 64;
  int tid = threadIdx.x;
  int w = tid >> 6;                  // 0=q, 1=k, 2=v
  int lane = tid & 63;

  __shared__ __align__(16) char lraw[66560];
  float (*ts)[68] = (float(*)[68])lraw;                 // [64][68]
  float (*Ws)[64] = (float(*)[64])(lraw + 17408);       // [192][64]

  for (int idx = tid; idx < 1024; idx += 192) {
    int row = idx >> 4, c4 = (idx & 15) * 4;
    size_t o = ((size_t)(bn * 1024 + i0 + row)) * 64 + c4;
    float4 v0 = *(const float4*)&part[o];
    float4 v1 = *(const float4*)&part[o + 2097152];
    float4 v2 = *(const float4*)&part[o + 2 * 2097152];
    float4 v3 = *(const float4*)&part[o + 3 * 2097152];
    float4 sv = make_float4(((v0.x + v1.x) + v2.x) + v3.x,
                            ((v0.y + v1.y) + v2.y) + v3.y,
                            ((v0.z + v1.z) + v2.z) + v3.z,
                            ((v0.w + v1.w) + v2.w) + v3.w);
    *(float4*)&ts[row][c4] = sv;
  }
  for (int idx = tid; idx < 3072; idx += 192) {
    int e = idx >> 4, c4 = (idx & 15) * 4;
    *(float4*)&Ws[e][c4] = *(const float4*)&W[(size_t)e * 64 + c4];
  }
  __syncthreads();

  float t[64];
#pragma unroll
  for (int c = 0; c < 16; ++c) {
    float4 v = *(const float4*)&ts[lane][c * 4];
    t[c * 4] = v.x; t[c * 4 + 1] = v.y; t[c * 4 + 2] = v.z; t[c * 4 + 3] = v.w;
  }
  int e0 = w * 64;
  short8 ph[8], pl[8];
#pragma unroll
  for (int ec = 0; ec < 8; ++ec) {
    short8 hh, ll;
#pragma unroll
    for (int k = 0; k < 8; ++k) {
      int e = e0 + ec * 8 + k;
      float acc = bias[e];
#pragma unroll
      for (int d = 0; d < 64; ++d) acc = fmaf(t[d], Ws[e][d], acc);
      unsigned short h = f32_to_bf16_rne(acc);
      hh[k] = (short)h;
      ll[k] = (short)f32_to_bf16_rne(acc - bf16_to_f32(h));
    }
    ph[ec] = hh; pl[ec] = ll;
  }
  __syncthreads();   // all waves done reading ts/Ws -> reuse LDS for out staging
  unsigned short* outH = (unsigned short*)(lraw + w * 18432);
  unsigned short* outL = (unsigned short*)(lraw + w * 18432 + 9216);
#pragma unroll
  for (int ec = 0; ec < 8; ++ec) {
    *(short8*)&outH[lane * 72 + ec * 8] = ph[ec];
    *(short8*)&outL[lane * 72 + ec * 8] = pl[ec];
  }
  // same-wave RAW below: no barrier needed
  if (w < 2) {
    unsigned short* dh = w ? kh : qh;
    unsigned short* dl = w ? kl : ql;
#pragma unroll
    for (int k = 0; k < 8; ++k) {
      int flat = (lane + k * 64) * 8;
      int row = flat >> 6, d = flat & 63;
      size_t go = ((size_t)(bn * 1024 + i0 + row)) * 64 + d;
      *(short8*)&dh[go] = *(const short8*)&outH[row * 72 + d];
      *(short8*)&dl[go] = *(const short8*)&outL[row * 72 + d];
    }
  } else {
    int db = lane >> 3, i8 = (lane & 7) * 8;
#pragma unroll
    for (int k = 0; k < 8; ++k) {
      int dd = db + k * 8;
      short8 hh, ll;
#pragma unroll
      for (int tt = 0; tt < 8; ++tt) {
        hh[tt] = (short)outH[(i8 + tt) * 72 + dd];
        ll[tt] = (short)outL[(i8 + tt) * 72 + dd];
      }
      size_t go = ((size_t)(bn * 64 + dd)) * 1024 + i0 + i8;
      *(short8*)&vth[go] = hh;
      *(short8*)&vtl[go] = ll;
    }
  }
}

// ---------------- 3. QKV topk v2: gathered 64-row tile, same core --------------
__global__ __launch_bounds__(192) void k_qkv_topk(const float* __restrict__ coutT,
    const int* __restrict__ idxb, const float* __restrict__ W, const float* __restrict__ bias,
    unsigned short* __restrict__ qh, unsigned short* __restrict__ ql,
    unsigned short* __restrict__ kh, unsigned short* __restrict__ kl,
    unsigned short* __restrict__ vth, unsigned short* __restrict__ vtl) {
  int blk = blockIdx.x;
  int bn = blk >> 4;
  int i0 = (blk & 15) * 64;
  int tid = threadIdx.x;
  int w = tid >> 6;
  int lane = tid & 63;

  __shared__ __align__(16) char lraw[66560];
  float (*ts)[68] = (float(*)[68])lraw;
  float (*Ws)[64] = (float(*)[64])(lraw + 17408);
  __shared__ int gs[64];

  if (tid < 64) {
    int row = tid;
    int p = idxb[bn * 256 + ((i0 + row) >> 2)] & 1023;
    int a = (row >> 1) & 1, b = row & 1;
    gs[row] = ((p >> 5) * 2 + a) * 64 + (p & 31) * 2 + b;
  }
  __syncthreads();
  for (int idx = tid; idx < 1024; idx += 192) {
    int row = idx >> 4, c4 = (idx & 15) * 4;
    *(float4*)&ts[row][c4] =
        *(const float4*)&coutT[((size_t)bn * 4096 + gs[row]) * 64 + c4];
  }
  for (int idx = tid; idx < 3072; idx += 192) {
    int e = idx >> 4, c4 = (idx & 15) * 4;
    *(float4*)&Ws[e][c4] = *(const float4*)&W[(size_t)e * 64 + c4];
  }
  __syncthreads();

  float t[64];
#pragma unroll
  for (int c = 0; c < 16; ++c) {
    float4 v = *(const float4*)&ts[lane][c * 4];
    t[c * 4] = v.x; t[c * 4 + 1] = v.y; t[c * 4 + 2] = v.z; t[c * 4 + 3] = v.w;
  }
  int e0 = w * 64;
  short8 ph[8], pl[8];
#pragma unroll
  for (int ec = 0; ec < 8; ++ec) {
    short8 hh, ll;
#pragma unroll
    for (int k = 0; k < 8; ++k) {
      int e = e0 + ec * 8 + k;
      float acc = bias[e];
#pragma unroll
      for (int d = 0; d < 64; ++d) acc = fmaf(t[d], Ws[e][d], acc);
      unsigned short h = f32_to_bf16_rne(acc);
      hh[k] = (short)h;
      ll[k] = (short)f32_to_bf16_rne(acc - bf16_to_f32(h));
    }
    ph[ec] = hh; pl[ec] = ll;
  }
  __syncthreads();
  unsigned short* outH = (unsigned short*)(lraw + w * 18432);
  unsigned short* outL = (unsigned short*)(lraw + w * 18432 + 9216);
#pragma unroll
  for (int ec = 0; ec < 8; ++ec) {
    *(short8*)&outH[lane * 72 + ec * 8] = ph[ec];
    *(short8*)&outL[lane * 72 + ec * 8] = pl[ec];
  }
  if (w < 2) {
    unsigned short* dh = w ? kh : qh;
    unsigned short* dl = w ? kl : ql;
#pragma unroll
    for (int k = 0; k < 8; ++k) {
      int flat = (lane + k * 64) * 8;
      int row = flat >> 6, d = flat & 63;
      size_t go = ((size_t)(bn * 1024 + i0 + row)) * 64 + d;
      *(short8*)&dh[go] = *(const short8*)&outH[row * 72 + d];
      *(short8*)&dl[go] = *(const short8*)&outL[row * 72 + d];
    }
  } else {
    int db = lane >> 3, i8 = (lane & 7) * 8;
#pragma unroll
    for (int k = 0; k < 8; ++k) {
      int dd = db + k * 8;
      short8 hh, ll;
#pragma unroll
      for (int tt = 0; tt < 8; ++tt) {
        hh[tt] = (short)outH[(i8 + tt) * 72 + dd];
        ll[tt] = (short)outL[(i8 + tt) * 72 + dd];
      }
      size_t go = ((size_t)(bn * 64 + dd)) * 1024 + i0 + i8;
      *(short8*)&vth[go] = hh;
      *(short8*)&vtl[go] = ll;
    }
  }
}

// ---------------- 4a. attention+score, split-bf16 MFMA (2-pass) ----------------
// LDS-staged Q/V per jt; XCD swizzle bn = blk&31. O emitted NATURAL [bn][i][d]
// as bf16 hi/lo (atth/attl) -> conv_up stages with contiguous short8 loads.
__global__ __launch_bounds__(256) void k_attn_score_mfma(
    const unsigned short* __restrict__ qh, const unsigned short* __restrict__ ql,
    const unsigned short* __restrict__ kh, const unsigned short* __restrict__ kl,
    const unsigned short* __restrict__ vth, const unsigned short* __restrict__ vtl,
    float* __restrict__ spart, unsigned short* __restrict__ atth,
    unsigned short* __restrict__ attl) {
  int blk = blockIdx.x;
  int bn = blk & 31;                 // XCD-locality: same bn -> idx ≡ bn (mod 8)
  int it = blk >> 5;
  int tid = threadIdx.x;
  int w = tid >> 6;
  int lane = tid & 63;
  int g = lane >> 4;
  int c = lane & 15;
  size_t qb = (size_t)bn << 16;      // *65536 (u16 elements)

  __shared__ __align__(16) unsigned short QH[64][72];
  __shared__ __align__(16) unsigned short QL[64][72];
  __shared__ __align__(16) unsigned short VH[64][72];
  __shared__ __align__(16) unsigned short VL[64][72];
  __shared__ __align__(16) unsigned short PH[64][72];
  __shared__ __align__(16) unsigned short PL[64][72];
  __shared__ float sacc[1024];
  for (int i2 = tid; i2 < 1024; i2 += 256) sacc[i2] = 0.f;

  int r0 = tid >> 3;                 // staging row 0..31
  int c8 = (tid & 7) * 8;            // staging col (u16)

  // K A-frags for this wave's 16 rows (A row = lane&15)
  int irow = it * 64 + w * 16 + c;
  short8 kfh[2], kfl[2];
#pragma unroll
  for (int ch = 0; ch < 2; ++ch) {
    kfh[ch] = *(const short8*)&kh[qb + (size_t)irow * 64 + ch * 32 + g * 8];
    kfl[ch] = *(const short8*)&kl[qb + (size_t)irow * 64 + ch * 32 + g * 8];
  }

  float m[4], lsum[4];
#pragma unroll
  for (int r = 0; r < 4; ++r) { m[r] = -3.0e38f; lsum[r] = 0.f; }

  // ---- pass 1: row max / denom (Q staged in LDS per jt) ----
  for (int jt = 0; jt < 16; ++jt) {
    __syncthreads();
#pragma unroll
    for (int rr = 0; rr < 2; ++rr) {
      int row = r0 + rr * 32;
      size_t go = qb + (size_t)(jt * 64 + row) * 64 + c8;
      *(short8*)&QH[row][c8] = *(const short8*)&qh[go];
      *(short8*)&QL[row][c8] = *(const short8*)&ql[go];
    }
    __syncthreads();
    f32x4 s[4];
#pragma unroll
    for (int su = 0; su < 4; ++su) s[su] = (f32x4){0.f, 0.f, 0.f, 0.f};
#pragma unroll
    for (int ch = 0; ch < 2; ++ch)
#pragma unroll
      for (int su = 0; su < 4; ++su) {
        short8 qfh = *(const short8*)&QH[su * 16 + c][ch * 32 + g * 8];
        short8 qfl = *(const short8*)&QL[su * 16 + c][ch * 32 + g * 8];
        s[su] = __builtin_amdgcn_mfma_f32_16x16x32_bf16(kfh[ch], qfh, s[su], 0, 0, 0);
        s[su] = __builtin_amdgcn_mfma_f32_16x16x32_bf16(kfl[ch], qfh, s[su], 0, 0, 0);
        s[su] = __builtin_amdgcn_mfma_f32_16x16x32_bf16(kfh[ch], qfl, s[su], 0, 0, 0);
      }
#pragma unroll
    for (int r = 0; r < 4; ++r) {
      float tm = fmaxf(fmaxf(s[0][r], s[1][r]), fmaxf(s[2][r], s[3][r]));
#pragma unroll
      for (int off = 1; off <= 8; off <<= 1) tm = fmaxf(tm, __shfl_xor(tm, off, 64));
      float mn = fmaxf(m[r], tm);
      float ts = ((expf(s[0][r] - mn) + expf(s[1][r] - mn)) +
                  expf(s[2][r] - mn)) + expf(s[3][r] - mn);
#pragma unroll
      for (int off = 1; off <= 8; off <<= 1) ts += __shfl_xor(ts, off, 64);
      lsum[r] = lsum[r] * expf(m[r] - mn) + ts;
      m[r] = mn;
    }
  }
  float inv[4];
#pragma unroll
  for (int r = 0; r < 4; ++r) inv[r] = 1.f / lsum[r];

  f32x4 oacc[4];
#pragma unroll
  for (int d = 0; d < 4; ++d) oacc[d] = (f32x4){0.f, 0.f, 0.f, 0.f};

  // ---- pass 2: P, scores, PV (Q+V staged in LDS per jt) ----
  for (int jt = 0; jt < 16; ++jt) {
    __syncthreads();
#pragma unroll
    for (int rr = 0; rr < 2; ++rr) {
      int row = r0 + rr * 32;
      size_t go = qb + (size_t)(jt * 64 + row) * 64 + c8;
      *(short8*)&QH[row][c8] = *(const short8*)&qh[go];
      *(short8*)&QL[row][c8] = *(const short8*)&ql[go];
      size_t vo = ((size_t)(bn * 64 + row)) * 1024 + jt * 64 + c8;
      *(short8*)&VH[row][c8] = *(const short8*)&vth[vo];
      *(short8*)&VL[row][c8] = *(const short8*)&vtl[vo];
    }
    __syncthreads();
    f32x4 s[4];
#pragma unroll
    for (int su = 0; su < 4; ++su) s[su] = (f32x4){0.f, 0.f, 0.f, 0.f};
#pragma unroll
    for (int ch = 0; ch < 2; ++ch)
#pragma unroll
      for (int su = 0; su < 4; ++su) {
        short8 qfh = *(const short8*)&QH[su * 16 + c][ch * 32 + g * 8];
        short8 qfl = *(const short8*)&QL[su * 16 + c][ch * 32 + g * 8];
        s[su] = __builtin_amdgcn_mfma_f32_16x16x32_bf16(kfh[ch], qfh, s[su], 0, 0, 0);
        s[su] = __builtin_amdgcn_mfma_f32_16x16x32_bf16(kfl[ch], qfh, s[su], 0, 0, 0);
        s[su] = __builtin_amdgcn_mfma_f32_16x16x32_bf16(kfh[ch], qfl, s[su], 0, 0, 0);
      }
#pragma unroll
    for (int su = 0; su < 4; ++su) {
      float p0 = expf(s[su][0] - m[0]) * inv[0];
      float p1 = expf(s[su][1] - m[1]) * inv[1];
      float p2 = expf(s[su][2] - m[2]) * inv[2];
      float p3 = expf(s[su][3] - m[3]) * inv[3];
      float cs = ((p0 + p1) + p2) + p3;
      cs += __shfl_xor(cs, 16, 64);
      cs += __shfl_xor(cs, 32, 64);
      if (g == 0) atomicAdd(&sacc[jt * 64 + su * 16 + c], cs);
      unsigned short h0 = f32_to_bf16_rne(p0);
      unsigned short h1 = f32_to_bf16_rne(p1);
      unsigned short h2 = f32_to_bf16_rne(p2);
      unsigned short h3 = f32_to_bf16_rne(p3);
      PH[w * 16 + g * 4 + 0][su * 16 + c] = h0;
      PH[w * 16 + g * 4 + 1][su * 16 + c] = h1;
      PH[w * 16 + g * 4 + 2][su * 16 + c] = h2;
      PH[w * 16 + g * 4 + 3][su * 16 + c] = h3;
      PL[w * 16 + g * 4 + 0][su * 16 + c] = f32_to_bf16_rne(p0 - bf16_to_f32(h0));
      PL[w * 16 + g * 4 + 1][su * 16 + c] = f32_to_bf16_rne(p1 - bf16_to_f32(h1));
      PL[w * 16 + g * 4 + 2][su * 16 + c] = f32_to_bf16_rne(p2 - bf16_to_f32(h2));
      PL[w * 16 + g * 4 + 3][su * 16 + c] = f32_to_bf16_rne(p3 - bf16_to_f32(h3));
    }
#pragma unroll
    for (int ch = 0; ch < 2; ++ch) {
      short8 pfh = *(const short8*)&PH[w * 16 + c][ch * 32 + g * 8];
      short8 pfl = *(const short8*)&PL[w * 16 + c][ch * 32 + g * 8];
#pragma unroll
      for (int d = 0; d < 4; ++d) {
        short8 vfh = *(const short8*)&VH[d * 16 + c][ch * 32 + g * 8];
        short8 vfl = *(const short8*)&VL[d * 16 + c][ch * 32 + g * 8];
        oacc[d] = __builtin_amdgcn_mfma_f32_16x16x32_bf16(vfh, pfh, oacc[d], 0, 0, 0);
        oacc[d] = __builtin_amdgcn_mfma_f32_16x16x32_bf16(vfl, pfh, oacc[d], 0, 0, 0);
        oacc[d] = __builtin_amdgcn_mfma_f32_16x16x32_bf16(vfh, pfl, oacc[d], 0, 0, 0);
      }
    }
  }
  // O natural [bn][i][d]: lane row i = it*64+w*16+c; cols d = dd*16+g*4+r
  {
    size_t obase = ((size_t)bn * 1024 + it * 64 + w * 16 + c) * 64;
#pragma unroll
    for (int dd = 0; dd < 4; ++dd) {
      short4v hh, ll;
#pragma unroll
      for (int r = 0; r < 4; ++r) {
        float v = oacc[dd][r];
        unsigned short h = f32_to_bf16_rne(v);
        hh[r] = (short)h;
        ll[r] = (short)f32_to_bf16_rne(v - bf16_to_f32(h));
      }
      *(short4v*)&atth[obase + dd * 16 + g * 4] = hh;
      *(short4v*)&attl[obase + dd * 16 + g * 4] = ll;
    }
  }
  __syncthreads();
  for (int i2 = tid; i2 < 1024; i2 += 256)
    spart[((size_t)bn * 16 + it) * 1024 + i2] = sacc[i2];
}

// ---------------- 4b. topk attention, split-bf16 MFMA (1-pass online) ----------
__global__ __launch_bounds__(256) void k_attn_online_mfma(
    const unsigned short* __restrict__ qh, const unsigned short* __restrict__ ql,
    const unsigned short* __restrict__ kh, const unsigned short* __restrict__ kl,
    const unsigned short* __restrict__ vth, const unsigned short* __restrict__ vtl,
    float* __restrict__ O) {
  int blk = blockIdx.x;
  int bn = blk & 31;                 // XCD-locality swizzle
  int it = blk >> 5;
  int tid = threadIdx.x;
  int w = tid >> 6;
  int lane = tid & 63;
  int g = lane >> 4;
  int c = lane & 15;
  size_t qb = (size_t)bn << 16;

  __shared__ __align__(16) unsigned short QH[64][72];
  __shared__ __align__(16) unsigned short QL[64][72];
  __shared__ __align__(16) unsigned short VH[64][72];
  __shared__ __align__(16) unsigned short VL[64][72];
  __shared__ __align__(16) unsigned short PH[64][72];
  __shared__ __align__(16) unsigned short PL[64][72];

  int r0 = tid >> 3;
  int c8 = (tid & 7) * 8;

  int irow = it * 64 + w * 16 + c;
  short8 kfh[2], kfl[2];
#pragma unroll
  for (int ch = 0; ch < 2; ++ch) {
    kfh[ch] = *(const short8*)&kh[qb + (size_t)irow * 64 + ch * 32 + g * 8];
    kfl[ch] = *(const short8*)&kl[qb + (size_t)irow * 64 + ch * 32 + g * 8];
  }

  float m[4], lsum[4];
  f32x4 oacc[4];
#pragma unroll
  for (int r = 0; r < 4; ++r) { m[r] = -3.0e38f; lsum[r] = 0.f; }
#pragma unroll
  for (int d = 0; d < 4; ++d) oacc[d] = (f32x4){0.f, 0.f, 0.f, 0.f};

  for (int jt = 0; jt < 16; ++jt) {
    __syncthreads();
#pragma unroll
    for (int rr = 0; rr < 2; ++rr) {
      int row = r0 + rr * 32;
      size_t go = qb + (size_t)(jt * 64 + row) * 64 + c8;
      *(short8*)&QH[row][c8] = *(const short8*)&qh[go];
      *(short8*)&QL[row][c8] = *(const short8*)&ql[go];
      size_t vo = ((size_t)(bn * 64 + row)) * 1024 + jt * 64 + c8;
      *(short8*)&VH[row][c8] = *(const short8*)&vth[vo];
      *(short8*)&VL[row][c8] = *(const short8*)&vtl[vo];
    }
    __syncthreads();
    f32x4 s[4];
#pragma unroll
    for (int su = 0; su < 4; ++su) s[su] = (f32x4){0.f, 0.f, 0.f, 0.f};
#pragma unroll
    for (int ch = 0; ch < 2; ++ch)
#pragma unroll
      for (int su = 0; su < 4; ++su) {
        short8 qfh = *(const short8*)&QH[su * 16 + c][ch * 32 + g * 8];
        short8 qfl = *(const short8*)&QL[su * 16 + c][ch * 32 + g * 8];
        s[su] = __builtin_amdgcn_mfma_f32_16x16x32_bf16(kfh[ch], qfh, s[su], 0, 0, 0);
        s[su] = __builtin_amdgcn_mfma_f32_16x16x32_bf16(kfl[ch], qfh, s[su], 0, 0, 0);
        s[su] = __builtin_amdgcn_mfma_f32_16x16x32_bf16(kfh[ch], qfl, s[su], 0, 0, 0);
      }
    float sc[4];
#pragma unroll
    for (int r = 0; r < 4; ++r) {
      float tm = fmaxf(fmaxf(s[0][r], s[1][r]), fmaxf(s[2][r], s[3][r]));
#pragma unroll
      for (int off = 1; off <= 8; off <<= 1) tm = fmaxf(tm, __shfl_xor(tm, off, 64));
      float mn = fmaxf(m[r], tm);
      sc[r] = expf(m[r] - mn);
      float p0 = expf(s[0][r] - mn);
      float p1 = expf(s[1][r] - mn);
      float p2 = expf(s[2][r] - mn);
      float p3 = expf(s[3][r] - mn);
      s[0][r] = p0; s[1][r] = p1; s[2][r] = p2; s[3][r] = p3;
      float ts = ((p0 + p1) + p2) + p3;
#pragma unroll
      for (int off = 1; off <= 8; off <<= 1) ts += __shfl_xor(ts, off, 64);
      lsum[r] = lsum[r] * sc[r] + ts;
      m[r] = mn;
    }
#pragma unroll
    for (int su = 0; su < 4; ++su) {
      unsigned short h0 = f32_to_bf16_rne(s[su][0]);
      unsigned short h1 = f32_to_bf16_rne(s[su][1]);
      unsigned short h2 = f32_to_bf16_rne(s[su][2]);
      unsigned short h3 = f32_to_bf16_rne(s[su][3]);
      PH[w * 16 + g * 4 + 0][su * 16 + c] = h0;
      PH[w * 16 + g * 4 + 1][su * 16 + c] = h1;
      PH[w * 16 + g * 4 + 2][su * 16 + c] = h2;
      PH[w * 16 + g * 4 + 3][su * 16 + c] = h3;
      PL[w * 16 + g * 4 + 0][su * 16 + c] = f32_to_bf16_rne(s[su][0] - bf16_to_f32(h0));
      PL[w * 16 + g * 4 + 1][su * 16 + c] = f32_to_bf16_rne(s[su][1] - bf16_to_f32(h1));
      PL[w * 16 + g * 4 + 2][su * 16 + c] = f32_to_bf16_rne(s[su][2] - bf16_to_f32(h2));
      PL[w * 16 + g * 4 + 3][su * 16 + c] = f32_to_bf16_rne(s[su][3] - bf16_to_f32(h3));
    }
    // rescale oacc by sc for col i=c (branchless select + shfl, rule #20 safe)
    float s01 = (c & 1) ? sc[1] : sc[0];
    float s23 = (c & 1) ? sc[3] : sc[2];
    float tmp = (c & 2) ? s23 : s01;
    float scc = __shfl(tmp, ((c >> 2) << 4) | c, 64);
#pragma unroll
    for (int d = 0; d < 4; ++d) oacc[d] *= scc;
#pragma unroll
    for (int ch = 0; ch < 2; ++ch) {
      short8 pfh = *(const short8*)&PH[w * 16 + c][ch * 32 + g * 8];
      short8 pfl = *(const short8*)&PL[w * 16 + c][ch * 32 + g * 8];
#pragma unroll
      for (int d = 0; d < 4; ++d) {
        short8 vfh = *(const short8*)&VH[d * 16 + c][ch * 32 + g * 8];
        short8 vfl = *(const short8*)&VL[d * 16 + c][ch * 32 + g * 8];
        oacc[d] = __builtin_amdgcn_mfma_f32_16x16x32_bf16(vfh, pfh, oacc[d], 0, 0, 0);
        oacc[d] = __builtin_amdgcn_mfma_f32_16x16x32_bf16(vfl, pfh, oacc[d], 0, 0, 0);
        oacc[d] = __builtin_amdgcn_mfma_f32_16x16x32_bf16(vfh, pfl, oacc[d], 0, 0, 0);
      }
    }
  }
  float i01 = (c & 1) ? (1.f / lsum[1]) : (1.f / lsum[0]);
  float i23 = (c & 1) ? (1.f / lsum[3]) : (1.f / lsum[2]);
  float itmp = (c & 2) ? i23 : i01;
  float invc = __shfl(itmp, ((c >> 2) << 4) | c, 64);
  // O natural [i][d]: lane col i = it*64+w*16+c; rows d = d*16+g*4+reg (contig f32x4)
#pragma unroll
  for (int d = 0; d < 4; ++d) {
    f32x4 o4 = oacc[d] * invc;
    *(f32x4*)&O[((size_t)bn * 1024 + it * 64 + w * 16 + c) * 64 + d * 16 + g * 4] = o4;
  }
}

// ---------------- 5. deterministic score reduction (16 partials) ----------------
__global__ __launch_bounds__(256) void k_score_reduce(const float* __restrict__ part,
                                                      float* __restrict__ score) {
  int j = blockIdx.x * 256 + threadIdx.x;   // 0..32767
  int bn = j >> 10, jj = j & 1023;
  float s = 0.f;
  for (int g = 0; g < 16; ++g) s += part[((size_t)bn * 16 + g) * 1024 + jj];
  score[j] = s;
}

// ---------------- 5b. default-init idx ----------------
__global__ __launch_bounds__(256) void k_idx_init(int* __restrict__ idx) {
  int j = blockIdx.x * 256 + threadIdx.x;
  idx[j] = j & 255;
}

// ---------------- 6. top-K by rank ----------------
__global__ __launch_bounds__(1024) void k_topk(const float* __restrict__ score,
                                               int* __restrict__ idxout) {
  int bn = blockIdx.x;
  int t = threadIdx.x;
  __shared__ float s[1024];
  s[t] = score[bn * 1024 + t];
  __syncthreads();
  float my = s[t];
  int rank = 0;
  for (int j = 0; j < 1024; ++j) {
    float o = s[j];
    rank += (o > my) || (o == my && j < t);
  }
  if (rank < 256) idxout[bn * 256 + rank] = t;
}

// ---------------- 7. transposed conv v6: natural atth, co-half split -----------
// grid 2048 = ((b*2 + r)*2 + coh)*32 + I; block: 1 oh row x 128 co x both s.
// Staging: contiguous short8 loads from atth[bn][i][d] (no conversion, no
// scalar gathers); vectorized LDS writes (conflict-free).
__global__ __launch_bounds__(256) void k_conv_up_mfma(
    const unsigned short* __restrict__ atth, const unsigned short* __restrict__ attl,
    const unsigned short* __restrict__ whi, const unsigned short* __restrict__ wlo,
    const float* __restrict__ bias, float* __restrict__ cout,
    float* __restrict__ coutT) {
  int blk = blockIdx.x;              // ((b*2 + r)*2 + coh)*32 + I
  int I = blk & 31;
  int coh = (blk >> 5) & 1;
  int r = (blk >> 6) & 1;
  int b = blk >> 7;
  int tid = threadIdx.x;
  int w = tid >> 6;                  // wave -> 32-co slab
  int lane = tid & 63;
  int lq = lane >> 4;
  int lr = lane & 15;

  __shared__ __align__(16) unsigned short AH[2][34][40];
  __shared__ __align__(16) unsigned short AL[2][34][40];

  f32x4 acc[2][2][2];                // [s][pfJ][cf]
#pragma unroll
  for (int s = 0; s < 2; ++s)
#pragma unroll
    for (int pf = 0; pf < 2; ++pf)
#pragma unroll
      for (int cf = 0; cf < 2; ++cf) acc[s][pf][cf] = (f32x4){0.f, 0.f, 0.f, 0.f};

  int ih0 = I + r - 1;
  const short8 zero8 = {0, 0, 0, 0, 0, 0, 0, 0};

  for (int ci0 = 0; ci0 < 256; ci0 += 32) {
    int n = ci0 >> 6, d0 = ci0 & 63;
    __syncthreads();
    // stage: 2 ih x 34 iw x 32 ci via contiguous short8 (272 vec loads)
    for (int idx = tid; idx < 272; idx += 256) {
      int q = idx & 3;
      int cell = idx >> 2;
      int rho = cell / 34;
      int col = cell - rho * 34;
      int ih = ih0 + rho;
      int iw = col - 1;
      short8 h = zero8, l = zero8;
      if ((unsigned)ih < 32u && (unsigned)iw < 32u) {
        size_t gg = ((size_t)((b * 4 + n) * 1024) + ih * 32 + iw) * 64 + d0 + q * 8;
        h = *(const short8*)&atth[gg];
        l = *(const short8*)&attl[gg];
      }
      *(short8*)&AH[rho][col][q * 8] = h;
      *(short8*)&AL[rho][col][q * 8] = l;
    }
    __syncthreads();
#pragma unroll
    for (int tap = 0; tap < 4; ++tap) {
      int a_ = tap >> 1, b_ = tap & 1;
      int rho = 1 - a_;
#pragma unroll
      for (int s = 0; s < 2; ++s) {
        int cls = r * 2 + s;
        size_t wb = (size_t)(cls * 4 + tap) * 65536;
        short8 bh[2], bl[2];
#pragma unroll
        for (int cf = 0; cf < 2; ++cf) {
          int co = coh * 128 + w * 32 + cf * 16 + lr;
          size_t off = wb + (size_t)co * 256 + ci0 + 8 * lq;
          bh[cf] = *(const short8*)&whi[off];
          bl[cf] = *(const short8*)&wlo[off];
        }
        short8 ah[2], al[2];
#pragma unroll
        for (int pf = 0; pf < 2; ++pf) {
          int col = pf * 16 + lr + s - b_ + 1;
          ah[pf] = *(const short8*)&AH[rho][col][8 * lq];
          al[pf] = *(const short8*)&AL[rho][col][8 * lq];
        }
#pragma unroll
        for (int pf = 0; pf < 2; ++pf)
#pragma unroll
          for (int cf = 0; cf < 2; ++cf) {
            acc[s][pf][cf] = __builtin_amdgcn_mfma_f32_16x16x32_bf16(ah[pf], bh[cf], acc[s][pf][cf], 0, 0, 0);
            acc[s][pf][cf] = __builtin_amdgcn_mfma_f32_16x16x32_bf16(al[pf], bh[cf], acc[s][pf][cf], 0, 0, 0);
            acc[s][pf][cf] = __builtin_amdgcn_mfma_f32_16x16x32_bf16(ah[pf], bl[cf], acc[s][pf][cf], 0, 0, 0);
          }
      }
    }
  }

  int oh = 2 * I + r;
#pragma unroll
  for (int cf = 0; cf < 2; ++cf) {
    int co = coh * 128 + w * 32 + cf * 16 + lr;
    float bv = bias[co];
    size_t cbase = ((size_t)b * 256 + co) * 4096 + (size_t)oh * 64;
    size_t tbase = (((size_t)(b * 4 + (co >> 6)) * 4096) + oh * 64) * 64 + (co & 63);
#pragma unroll
    for (int pf = 0; pf < 2; ++pf)
#pragma unroll
      for (int reg = 0; reg < 4; ++reg) {
        int J = pf * 16 + lq * 4 + reg;
        float v0 = acc[0][pf][cf][reg] + bv;
        float v1 = acc[1][pf][cf][reg] + bv;
        *(float2*)&cout[cbase + 2 * J] = make_float2(v0, v1);
        coutT[tbase + (size_t)(2 * J) * 64] = v0;
        coutT[tbase + (size_t)(2 * J + 1) * 64] = v1;
      }
  }
}

// ---------------- 8. y = coarse_out + region ----------------
__global__ __launch_bounds__(256) void k_ybuild(const float* __restrict__ cout,
                                                float* __restrict__ y) {
  size_t e = (size_t)blockIdx.x * 256 + threadIdx.x;
  int flat = (int)(e & 4095);
  size_t bc = e >> 12;
  int p = flat >> 2, ab = flat & 3;
  int a = ab >> 1, bi = ab & 1;
  int src = ((p >> 5) * 2 + a) * 64 + (p & 31) * 2 + bi;
  const float* cb = cout + bc * 4096;
  y[e] = cb[flat] + cb[src];
}

// ---------------- 9. scatter-add attended tokens ----------------
__global__ __launch_bounds__(256) void k_scatter(const float* __restrict__ out2,
    const int* __restrict__ idx, float* __restrict__ y) {
  int e = blockIdx.x * 256 + threadIdx.x;
  int d = e & 63;
  int r = e >> 6;
  int ab = r & 3;
  int r2 = r >> 2;
  int kk = r2 & 255;
  int bn = r2 >> 8;
  int b = bn >> 2, n = bn & 3;
  int p = idx[bn * 256 + kk] & 1023;
  int flat = p * 4 + ab;
  int t = kk * 4 + ab;
  y[((size_t)(b * 256 + n * 64 + d)) * 4096 + flat] +=
      out2[((size_t)bn * 1024 + t) * 64 + d];
}

// ---------------- 10. depthwise 3x3 + BN + relu6 ----------------
__global__ __launch_bounds__(256) void k_dw(const float* __restrict__ y,
    const float* __restrict__ w, const float* __restrict__ g, const float* __restrict__ bb,
    const float* __restrict__ mm, const float* __restrict__ vv, float* __restrict__ t1) {
  size_t e = (size_t)blockIdx.x * 256 + threadIdx.x;
  int pix = (int)(e & 4095);
  int c = (int)((e >> 12) & 255);
  int oh = pix >> 6, ow = pix & 63;
  const float* yb = y + (e - pix);
  float acc = 0.f;
#pragma unroll
  for (int kh = 0; kh < 3; ++kh) {
    int ih = oh - 1 + kh;
    if ((unsigned)ih >= 64u) continue;
#pragma unroll
    for (int kw = 0; kw < 3; ++kw) {
      int iw = ow - 1 + kw;
      if ((unsigned)iw >= 64u) continue;
      acc = fmaf(yb[ih * 64 + iw], w[c * 9 + kh * 3 + kw], acc);
    }
  }
  float s = g[c] * rsqrtf(vv[c] + 1e-5f);
  float val = acc * s + (bb[c] - mm[c] * s);
  t1[e] = fminf(fmaxf(val, 0.f), 6.f);
}

// ---------------- 11. pointwise v2: 4 co per block, 16 FMA per 16B load --------
__global__ __launch_bounds__(256) void k_pw2(const float* __restrict__ t1,
    const float* __restrict__ w, const float* __restrict__ g, const float* __restrict__ bb,
    const float* __restrict__ mm, const float* __restrict__ vv, float* __restrict__ out) {
  int blk = blockIdx.x;              // (b*64 + cog)*4 + tile
  int tile = blk & 3;
  int cog = (blk >> 2) & 63;
  int b = blk >> 8;
  int co0 = cog * 4;
  int t = threadIdx.x;
  __shared__ float wl[256][4];
  for (int idx = t; idx < 1024; idx += 256) {
    int cof = idx >> 8;
    int ci = idx & 255;
    wl[ci][cof] = w[(co0 + cof) * 256 + ci];
  }
  __syncthreads();
  int px0 = tile * 1024 + t * 4;
  const float* tb = t1 + (size_t)b * 256 * 4096 + px0;
  float acc[4][4];
#pragma unroll
  for (int a = 0; a < 4; ++a)
#pragma unroll
    for (int jj = 0; jj < 4; ++jj) acc[a][jj] = 0.f;
  for (int ci = 0; ci < 256; ++ci) {
    float4 tv = *(const float4*)(tb + (size_t)ci * 4096);
    float4 wv = *(const float4*)&wl[ci][0];
    acc[0][0] = fmaf(tv.x, wv.x, acc[0][0]); acc[0][1] = fmaf(tv.y, wv.x, acc[0][1]);
    acc[0][2] = fmaf(tv.z, wv.x, acc[0][2]); acc[0][3] = fmaf(tv.w, wv.x, acc[0][3]);
    acc[1][0] = fmaf(tv.x, wv.y, acc[1][0]); acc[1][1] = fmaf(tv.y, wv.y, acc[1][1]);
    acc[1][2] = fmaf(tv.z, wv.y, acc[1][2]); acc[1][3] = fmaf(tv.w, wv.y, acc[1][3]);
    acc[2][0] = fmaf(tv.x, wv.z, acc[2][0]); acc[2][1] = fmaf(tv.y, wv.z, acc[2][1]);
    acc[2][2] = fmaf(tv.z, wv.z, acc[2][2]); acc[2][3] = fmaf(tv.w, wv.z, acc[2][3]);
    acc[3][0] = fmaf(tv.x, wv.w, acc[3][0]); acc[3][1] = fmaf(tv.y, wv.w, acc[3][1]);
    acc[3][2] = fmaf(tv.z, wv.w, acc[3][2]); acc[3][3] = fmaf(tv.w, wv.w, acc[3][3]);
  }
#pragma unroll
  for (int a = 0; a < 4; ++a) {
    int co = co0 + a;
    float s = g[co] * rsqrtf(vv[co] + 1e-5f);
    float bias = bb[co] - mm[co] * s;
    float4 o4;
    o4.x = fminf(fmaxf(acc[a][0] * s + bias, 0.f), 6.f);
    o4.y = fminf(fmaxf(acc[a][1] * s + bias, 0.f), 6.f);
    o4.z = fminf(fmaxf(acc[a][2] * s + bias, 0.f), 6.f);
    o4.w = fminf(fmaxf(acc[a][3] * s + bias, 0.f), 6.f);
    *(float4*)(out + ((size_t)(b * 256 + co)) * 4096 + px0) = o4;
  }
}

// ---------------- launcher ----------------
extern "C" void kernel_launch(void* const* d_in, const int* in_sizes, int n_in,
                              void* d_out, int out_size, void* d_ws, size_t ws_size,
                              hipStream_t stream) {
  if (ws_size < WS_FLOATS * sizeof(float)) return;

  const float* x      = (const float*)d_in[0];
  const float* down_w = (const float*)d_in[1];
  const float* down_b = (const float*)d_in[2];
  const float* up_w   = (const float*)d_in[3];
  const float* up_b   = (const float*)d_in[4];
  const float* cqkv_w = (const float*)d_in[5];
  const float* cqkv_b = (const float*)d_in[6];
  const float* tqkv_w = (const float*)d_in[7];
  const float* tqkv_b = (const float*)d_in[8];
  const float* dww    = (const float*)d_in[9];
  const float* bn1g   = (const float*)d_in[10];
  const float* bn1b   = (const float*)d_in[11];
  const float* bn1m   = (const float*)d_in[12];
  const float* bn1v   = (const float*)d_in[13];
  const float* pww    = (const float*)d_in[14];
  const float* bn2g   = (const float*)d_in[15];
  const float* bn2b   = (const float*)d_in[16];
  const float* bn2m   = (const float*)d_in[17];
  const float* bn2v   = (const float*)d_in[18];

  float* ws    = (float*)d_ws;
  float* att   = ws + OFF_ATT;
  float* spart = ws + OFF_SPART;
  float* score = ws + OFF_SCORE;
  int*   idx   = (int*)(ws + OFF_IDX);
  float* cout  = ws + OFF_COUT;
  float* y     = ws + OFF_Y;
  float* t1    = ws + OFF_T1;
  unsigned short* atth = (unsigned short*)(ws + OFF_SPART + 2097152);  // O natural hi (2M u16)
  unsigned short* attl = (unsigned short*)(ws + OFF_SPART + 3145728);  // O natural lo (2M u16)
  unsigned short* whi  = (unsigned short*)(ws + OFF_XD);            // up-w hi
  unsigned short* wlo  = (unsigned short*)(ws + OFF_XD + 524288);   // up-w lo
  unsigned short* dwhi = (unsigned short*)(ws + OFF_SPART);             // down-w hi (dead after conv_down)
  unsigned short* dwlo = (unsigned short*)(ws + OFF_SPART + 524288);    // down-w lo
  unsigned short* xbh  = (unsigned short*)(ws + OFF_Q);   // x hi (Q..K regions, dead after conv_down)
  unsigned short* xbl  = (unsigned short*)(ws + OFF_V);   // x lo (V..ATT regions, dead after conv_down)
  unsigned short* qh   = (unsigned short*)(ws + OFF_Q);
  unsigned short* ql   = (unsigned short*)(ws + OFF_Q + 1048576);
  unsigned short* kh   = (unsigned short*)(ws + OFF_K);
  unsigned short* kl   = (unsigned short*)(ws + OFF_K + 1048576);
  unsigned short* vth  = (unsigned short*)(ws + OFF_V);
  unsigned short* vtl  = (unsigned short*)(ws + OFF_V + 1048576);
  float* coutT = ws + OFF_T1;                // t1 region dead until k_dw
  float* dpart = ws + OFF_Y;                 // 4 x 2M ci-split partials (dead until k_ybuild)

  k_x2bf<<<1024, 256, 0, stream>>>(x, xbh, xbl);
  k_wt_dnb<<<4096, 256, 0, stream>>>(down_w, dwhi, dwlo);
  k_conv_down_mfma<<<4096, 256, 0, stream>>>(xbh, xbl, dwhi, dwlo, down_b, dpart);
  k_qkv_coarse<<<512, 192, 0, stream>>>(dpart, cqkv_w, cqkv_b, qh, ql, kh, kl, vth, vtl);
  k_wt_upb<<<4096, 256, 0, stream>>>(up_w, whi, wlo);
  k_attn_score_mfma<<<512, 256, 0, stream>>>(qh, ql, kh, kl, vth, vtl, spart, atth, attl);
  k_score_reduce<<<128, 256, 0, stream>>>(spart, score);
  k_idx_init<<<32, 256, 0, stream>>>(idx);
  k_topk<<<32, 1024, 0, stream>>>(score, idx);
  k_conv_up_mfma<<<2048, 256, 0, stream>>>(atth, attl, whi, wlo, up_b, cout, coutT);
  k_qkv_topk<<<512, 192, 0, stream>>>(coutT, idx, tqkv_w, tqkv_b, qh, ql, kh, kl, vth, vtl);
  k_attn_online_mfma<<<512, 256, 0, stream>>>(qh, ql, kh, kl, vth, vtl, att);
  k_ybuild<<<32768, 256, 0, stream>>>(cout, y);
  k_scatter<<<8192, 256, 0, stream>>>(att, idx, y);
  k_dw<<<32768, 256, 0, stream>>>(y, dww, bn1g, bn1b, bn1m, bn1v, t1);
  k_pw2<<<2048, 256, 0, stream>>>(t1, pww, bn2g, bn2b, bn2m, bn2v, (float*)d_out);
}

// Round 11
// 880.713 us; speedup vs baseline: 1.1363x; 1.1363x over previous
//
#include <hip/hip_runtime.h>

typedef short short8 __attribute__((ext_vector_type(8)));
typedef short short4v __attribute__((ext_vector_type(4)));
typedef float f32x4 __attribute__((ext_vector_type(4)));

__device__ inline unsigned short f32_to_bf16_rne(float f) {
  unsigned int u = __float_as_uint(f);
  unsigned int r = (u + 0x7fffu + ((u >> 16) & 1u)) >> 16;
  return (unsigned short)r;
}
__device__ inline float bf16_to_f32(unsigned short h) {
  return __uint_as_float(((unsigned int)h) << 16);
}

// ---------------- workspace layout (float offsets) ----------------
// bf16 qkv: qh/ql -> Q region, kh/kl -> K region, vth/vtl (V^T [d][j]) -> V region
// att (O, fp32) -> ATT.  spart -> SPART; atth/attl (bf16 O natural [bn][i][d])
// at SPART+2M/+3M.  score / idx / cout / y / t1
// aliases: whi/wlo (up-w) -> XD; dwhi/dwlo (down-w) -> SPART (dead before spart use)
//          xbh -> Q..K, xbl -> V..ATT (dead after conv_down)
//          coutT -> t1 region; dpart -> y region
constexpr size_t OFF_XD    = 0;
constexpr size_t OFF_Q     = 2097152;
constexpr size_t OFF_K     = 4194304;
constexpr size_t OFF_V     = 6291456;
constexpr size_t OFF_ATT   = 8388608;
constexpr size_t OFF_SPART = 10485760;
constexpr size_t OFF_SCORE = 14680064;
constexpr size_t OFF_IDX   = 14712832;
constexpr size_t OFF_COUT  = 14721024;
constexpr size_t OFF_Y     = 23109632;
constexpr size_t OFF_T1    = 31498240;
constexpr size_t WS_FLOATS = 39886848;

// ---------------- 0a. x NCHW -> NHWC split-bf16 (xbh/xbl [b][ih][iw][ci]) ------
__global__ __launch_bounds__(256) void k_x2bf(const float* __restrict__ x,
    unsigned short* __restrict__ xbh, unsigned short* __restrict__ xbl) {
  int bid = blockIdx.x;              // b*128 + ih*2 + iwh
  int b = bid >> 7;
  int ih = (bid >> 1) & 63;
  int iwh = bid & 1;
  int t = threadIdx.x;
  __shared__ float ts[256][33];
  for (int it = 0; it < 32; ++it) {
    int idx = it * 256 + t;
    int ci = idx >> 5;
    int iwl = idx & 31;
    ts[ci][iwl] = x[(((size_t)(b * 256 + ci) * 64 + ih) * 64) + iwh * 32 + iwl];
  }
  __syncthreads();
  int iwl = t >> 3;
  int cb = (t & 7) * 32;
  size_t base = (((size_t)(b * 64 + ih) * 64) + iwh * 32 + iwl) * 256 + cb;
#pragma unroll
  for (int j = 0; j < 32; j += 2) {
    float v0 = ts[cb + j][iwl];
    float v1 = ts[cb + j + 1][iwl];
    unsigned short h0 = f32_to_bf16_rne(v0);
    unsigned short h1 = f32_to_bf16_rne(v1);
    unsigned short l0 = f32_to_bf16_rne(v0 - bf16_to_f32(h0));
    unsigned short l1 = f32_to_bf16_rne(v1 - bf16_to_f32(h1));
    *(ushort2*)&xbh[base + j] = make_ushort2(h0, h1);
    *(ushort2*)&xbl[base + j] = make_ushort2(l0, l1);
  }
}

// ---------------- 0b. down_w -> split-bf16 dwhi/dwlo [kk][co][ci] --------------
__global__ __launch_bounds__(256) void k_wt_dnb(const float* __restrict__ w,
    unsigned short* __restrict__ dwhi, unsigned short* __restrict__ dwlo) {
  int idx = blockIdx.x * 256 + threadIdx.x;   // 1,048,576 = (kk*256+co)*256+ci
  int ci = idx & 255;
  int co = (idx >> 8) & 255;
  int kk = idx >> 16;
  float v = w[((size_t)(co * 256 + ci)) * 16 + kk];
  unsigned short h = f32_to_bf16_rne(v);
  unsigned short l = f32_to_bf16_rne(v - bf16_to_f32(h));
  dwhi[idx] = h;
  dwlo[idx] = l;
}

// ---------------- 0c. up_w -> split-bf16 whi/wlo [cls][tap][co][ci] ----------
__global__ __launch_bounds__(256) void k_wt_upb(const float* __restrict__ w,
    unsigned short* __restrict__ whi, unsigned short* __restrict__ wlo) {
  int idx = blockIdx.x * 256 + threadIdx.x;   // 1,048,576
  int ci = idx & 255;
  int co = (idx >> 8) & 255;
  int tp = idx >> 16;                         // 0..15
  int cls = tp >> 2, tap = tp & 3;
  int r = cls >> 1, s = cls & 1;
  int a_ = tap >> 1, b_ = tap & 1;
  int kh = a_ ? (r ? 2 : 3) : (r ? 0 : 1);
  int kw = b_ ? (s ? 2 : 3) : (s ? 0 : 1);
  float v = w[((size_t)(ci * 256 + co)) * 16 + kh * 4 + kw];
  unsigned short h = f32_to_bf16_rne(v);
  unsigned short l = f32_to_bf16_rne(v - bf16_to_f32(h));
  whi[idx] = h;
  wlo[idx] = l;
}

// ---------------- 1. down conv: split-bf16 MFMA implicit GEMM ------------------
__global__ __launch_bounds__(256) void k_conv_down_mfma(
    const unsigned short* __restrict__ xbh, const unsigned short* __restrict__ xbl,
    const unsigned short* __restrict__ dwhi, const unsigned short* __restrict__ dwlo,
    const float* __restrict__ bias, float* __restrict__ part) {
  int blk = blockIdx.x;              // ((ks*8 + b)*4 + ct)*32 + pt
  int pt = blk & 31;
  int ct = (blk >> 5) & 3;
  int b = (blk >> 7) & 7;
  int ks = blk >> 10;
  int oh2 = pt >> 1;                 // 0..15 (pair of oh rows)
  int owh = pt & 1;                  // ow half (16)
  int tid = threadIdx.x;
  int w = tid >> 6;                  // wave 0..3 -> co quarter
  int lane = tid & 63;
  int lq = lane >> 4;
  int lr = lane & 15;
  int co = ct * 64 + w * 16 + lr;

  __shared__ __align__(16) unsigned short AH[6][34][40];
  __shared__ __align__(16) unsigned short AL[6][34][40];

  f32x4 acc[2];
  acc[0] = (f32x4){0.f, 0.f, 0.f, 0.f};
  acc[1] = (f32x4){0.f, 0.f, 0.f, 0.f};

  int ih0 = 4 * oh2 - 1;             // tile row 0
  int iw0 = owh * 32 - 1;            // tile col 0
  const short8 zero8 = {0, 0, 0, 0, 0, 0, 0, 0};

  for (int ch = 0; ch < 2; ++ch) {
    int ci0 = ks * 64 + ch * 32;
    __syncthreads();
    for (int idx = tid; idx < 6 * 34 * 4; idx += 256) {
      int q = idx & 3;
      int cell = idx >> 2;
      int row = cell / 34;
      int col = cell - row * 34;
      int ih = ih0 + row;
      int iw = iw0 + col;
      short8 h = zero8, l = zero8;
      if ((unsigned)ih < 64u && (unsigned)iw < 64u) {
        size_t gg = (((size_t)(b * 64 + ih) * 64) + iw) * 256 + ci0 + q * 8;
        h = *(const short8*)&xbh[gg];
        l = *(const short8*)&xbl[gg];
      }
      *(short8*)&AH[row][col][q * 8] = h;
      *(short8*)&AL[row][col][q * 8] = l;
    }
    __syncthreads();
#pragma unroll
    for (int tap = 0; tap < 16; ++tap) {
      int kh = tap >> 2, kw = tap & 3;
      size_t woff = ((size_t)tap * 256 + co) * 256 + ci0 + 8 * lq;
      short8 bh = *(const short8*)&dwhi[woff];
      short8 bl = *(const short8*)&dwlo[woff];
#pragma unroll
      for (int pf = 0; pf < 2; ++pf) {
        short8 ah = *(const short8*)&AH[2 * pf + kh][2 * lr + kw][8 * lq];
        short8 al = *(const short8*)&AL[2 * pf + kh][2 * lr + kw][8 * lq];
        acc[pf] = __builtin_amdgcn_mfma_f32_16x16x32_bf16(ah, bh, acc[pf], 0, 0, 0);
        acc[pf] = __builtin_amdgcn_mfma_f32_16x16x32_bf16(al, bh, acc[pf], 0, 0, 0);
        acc[pf] = __builtin_amdgcn_mfma_f32_16x16x32_bf16(ah, bl, acc[pf], 0, 0, 0);
      }
    }
  }

  float bv = (ks == 0) ? bias[co] : 0.f;
  int bn = b * 4 + ct;
  int d = w * 16 + lr;
  float* pb = part + (size_t)ks * 2097152;
#pragma unroll
  for (int pf = 0; pf < 2; ++pf) {
    int oh = 2 * oh2 + pf;
#pragma unroll
    for (int reg = 0; reg < 4; ++reg) {
      int ow = owh * 16 + lq * 4 + reg;
      int pix = oh * 32 + ow;
      pb[((size_t)bn * 1024 + pix) * 64 + d] = acc[pf][reg] + bv;
    }
  }
}

// ---------------- 2. QKV coarse v2: 64-row tile, waves = (q,k,v), coalesced ----
__global__ __launch_bounds__(192) void k_qkv_coarse(const float* __restrict__ part,
    const float* __restrict__ W, const float* __restrict__ bias,
    unsigned short* __restrict__ qh, unsigned short* __restrict__ ql,
    unsigned short* __restrict__ kh, unsigned short* __restrict__ kl,
    unsigned short* __restrict__ vth, unsigned short* __restrict__ vtl) {
  int blk = blockIdx.x;
  int bn = blk >> 4;
  int i0 = (blk & 15) * 64;
  int tid = threadIdx.x;
  int w = tid >> 6;                  // 0=q, 1=k, 2=v
  int lane = tid & 63;

  __shared__ __align__(16) char lraw[66560];
  float (*ts)[68] = (float(*)[68])lraw;                 // [64][68]
  float (*Ws)[64] = (float(*)[64])(lraw + 17408);       // [192][64]

  for (int idx = tid; idx < 1024; idx += 192) {
    int row = idx >> 4, c4 = (idx & 15) * 4;
    size_t o = ((size_t)(bn * 1024 + i0 + row)) * 64 + c4;
    float4 v0 = *(const float4*)&part[o];
    float4 v1 = *(const float4*)&part[o + 2097152];
    float4 v2 = *(const float4*)&part[o + 2 * 2097152];
    float4 v3 = *(const float4*)&part[o + 3 * 2097152];
    float4 sv = make_float4(((v0.x + v1.x) + v2.x) + v3.x,
                            ((v0.y + v1.y) + v2.y) + v3.y,
                            ((v0.z + v1.z) + v2.z) + v3.z,
                            ((v0.w + v1.w) + v2.w) + v3.w);
    *(float4*)&ts[row][c4] = sv;
  }
  for (int idx = tid; idx < 3072; idx += 192) {
    int e = idx >> 4, c4 = (idx & 15) * 4;
    *(float4*)&Ws[e][c4] = *(const float4*)&W[(size_t)e * 64 + c4];
  }
  __syncthreads();

  float t[64];
#pragma unroll
  for (int c = 0; c < 16; ++c) {
    float4 v = *(const float4*)&ts[lane][c * 4];
    t[c * 4] = v.x; t[c * 4 + 1] = v.y; t[c * 4 + 2] = v.z; t[c * 4 + 3] = v.w;
  }
  int e0 = w * 64;
  short8 ph[8], pl[8];
#pragma unroll
  for (int ec = 0; ec < 8; ++ec) {
    short8 hh, ll;
#pragma unroll
    for (int k = 0; k < 8; ++k) {
      int e = e0 + ec * 8 + k;
      float acc = bias[e];
#pragma unroll
      for (int d = 0; d < 64; ++d) acc = fmaf(t[d], Ws[e][d], acc);
      unsigned short h = f32_to_bf16_rne(acc);
      hh[k] = (short)h;
      ll[k] = (short)f32_to_bf16_rne(acc - bf16_to_f32(h));
    }
    ph[ec] = hh; pl[ec] = ll;
  }
  __syncthreads();   // all waves done reading ts/Ws -> reuse LDS for out staging
  unsigned short* outH = (unsigned short*)(lraw + w * 18432);
  unsigned short* outL = (unsigned short*)(lraw + w * 18432 + 9216);
#pragma unroll
  for (int ec = 0; ec < 8; ++ec) {
    *(short8*)&outH[lane * 72 + ec * 8] = ph[ec];
    *(short8*)&outL[lane * 72 + ec * 8] = pl[ec];
  }
  // same-wave RAW below: no barrier needed
  if (w < 2) {
    unsigned short* dh = w ? kh : qh;
    unsigned short* dl = w ? kl : ql;
#pragma unroll
    for (int k = 0; k < 8; ++k) {
      int flat = (lane + k * 64) * 8;
      int row = flat >> 6, d = flat & 63;
      size_t go = ((size_t)(bn * 1024 + i0 + row)) * 64 + d;
      *(short8*)&dh[go] = *(const short8*)&outH[row * 72 + d];
      *(short8*)&dl[go] = *(const short8*)&outL[row * 72 + d];
    }
  } else {
    int db = lane >> 3, i8 = (lane & 7) * 8;
#pragma unroll
    for (int k = 0; k < 8; ++k) {
      int dd = db + k * 8;
      short8 hh, ll;
#pragma unroll
      for (int tt = 0; tt < 8; ++tt) {
        hh[tt] = (short)outH[(i8 + tt) * 72 + dd];
        ll[tt] = (short)outL[(i8 + tt) * 72 + dd];
      }
      size_t go = ((size_t)(bn * 64 + dd)) * 1024 + i0 + i8;
      *(short8*)&vth[go] = hh;
      *(short8*)&vtl[go] = ll;
    }
  }
}

// ---------------- 3. QKV topk v2: gathered 64-row tile, same core --------------
__global__ __launch_bounds__(192) void k_qkv_topk(const float* __restrict__ coutT,
    const int* __restrict__ idxb, const float* __restrict__ W, const float* __restrict__ bias,
    unsigned short* __restrict__ qh, unsigned short* __restrict__ ql,
    unsigned short* __restrict__ kh, unsigned short* __restrict__ kl,
    unsigned short* __restrict__ vth, unsigned short* __restrict__ vtl) {
  int blk = blockIdx.x;
  int bn = blk >> 4;
  int i0 = (blk & 15) * 64;
  int tid = threadIdx.x;
  int w = tid >> 6;
  int lane = tid & 63;

  __shared__ __align__(16) char lraw[66560];
  float (*ts)[68] = (float(*)[68])lraw;
  float (*Ws)[64] = (float(*)[64])(lraw + 17408);
  __shared__ int gs[64];

  if (tid < 64) {
    int row = tid;
    int p = idxb[bn * 256 + ((i0 + row) >> 2)] & 1023;
    int a = (row >> 1) & 1, b = row & 1;
    gs[row] = ((p >> 5) * 2 + a) * 64 + (p & 31) * 2 + b;
  }
  __syncthreads();
  for (int idx = tid; idx < 1024; idx += 192) {
    int row = idx >> 4, c4 = (idx & 15) * 4;
    *(float4*)&ts[row][c4] =
        *(const float4*)&coutT[((size_t)bn * 4096 + gs[row]) * 64 + c4];
  }
  for (int idx = tid; idx < 3072; idx += 192) {
    int e = idx >> 4, c4 = (idx & 15) * 4;
    *(float4*)&Ws[e][c4] = *(const float4*)&W[(size_t)e * 64 + c4];
  }
  __syncthreads();

  float t[64];
#pragma unroll
  for (int c = 0; c < 16; ++c) {
    float4 v = *(const float4*)&ts[lane][c * 4];
    t[c * 4] = v.x; t[c * 4 + 1] = v.y; t[c * 4 + 2] = v.z; t[c * 4 + 3] = v.w;
  }
  int e0 = w * 64;
  short8 ph[8], pl[8];
#pragma unroll
  for (int ec = 0; ec < 8; ++ec) {
    short8 hh, ll;
#pragma unroll
    for (int k = 0; k < 8; ++k) {
      int e = e0 + ec * 8 + k;
      float acc = bias[e];
#pragma unroll
      for (int d = 0; d < 64; ++d) acc = fmaf(t[d], Ws[e][d], acc);
      unsigned short h = f32_to_bf16_rne(acc);
      hh[k] = (short)h;
      ll[k] = (short)f32_to_bf16_rne(acc - bf16_to_f32(h));
    }
    ph[ec] = hh; pl[ec] = ll;
  }
  __syncthreads();
  unsigned short* outH = (unsigned short*)(lraw + w * 18432);
  unsigned short* outL = (unsigned short*)(lraw + w * 18432 + 9216);
#pragma unroll
  for (int ec = 0; ec < 8; ++ec) {
    *(short8*)&outH[lane * 72 + ec * 8] = ph[ec];
    *(short8*)&outL[lane * 72 + ec * 8] = pl[ec];
  }
  if (w < 2) {
    unsigned short* dh = w ? kh : qh;
    unsigned short* dl = w ? kl : ql;
#pragma unroll
    for (int k = 0; k < 8; ++k) {
      int flat = (lane + k * 64) * 8;
      int row = flat >> 6, d = flat & 63;
      size_t go = ((size_t)(bn * 1024 + i0 + row)) * 64 + d;
      *(short8*)&dh[go] = *(const short8*)&outH[row * 72 + d];
      *(short8*)&dl[go] = *(const short8*)&outL[row * 72 + d];
    }
  } else {
    int db = lane >> 3, i8 = (lane & 7) * 8;
#pragma unroll
    for (int k = 0; k < 8; ++k) {
      int dd = db + k * 8;
      short8 hh, ll;
#pragma unroll
      for (int tt = 0; tt < 8; ++tt) {
        hh[tt] = (short)outH[(i8 + tt) * 72 + dd];
        ll[tt] = (short)outL[(i8 + tt) * 72 + dd];
      }
      size_t go = ((size_t)(bn * 64 + dd)) * 1024 + i0 + i8;
      *(short8*)&vth[go] = hh;
      *(short8*)&vtl[go] = ll;
    }
  }
}

// ---------------- 4a. attention+score, split-bf16 MFMA (2-pass) ----------------
// LDS-staged Q/V per jt; XCD swizzle bn = blk&31. O emitted NATURAL [bn][i][d]
// as bf16 hi/lo (atth/attl) -> conv_up stages with contiguous short8 loads.
__global__ __launch_bounds__(256) void k_attn_score_mfma(
    const unsigned short* __restrict__ qh, const unsigned short* __restrict__ ql,
    const unsigned short* __restrict__ kh, const unsigned short* __restrict__ kl,
    const unsigned short* __restrict__ vth, const unsigned short* __restrict__ vtl,
    float* __restrict__ spart, unsigned short* __restrict__ atth,
    unsigned short* __restrict__ attl) {
  int blk = blockIdx.x;
  int bn = blk & 31;                 // XCD-locality: same bn -> idx ≡ bn (mod 8)
  int it = blk >> 5;
  int tid = threadIdx.x;
  int w = tid >> 6;
  int lane = tid & 63;
  int g = lane >> 4;
  int c = lane & 15;
  size_t qb = (size_t)bn << 16;      // *65536 (u16 elements)

  __shared__ __align__(16) unsigned short QH[64][72];
  __shared__ __align__(16) unsigned short QL[64][72];
  __shared__ __align__(16) unsigned short VH[64][72];
  __shared__ __align__(16) unsigned short VL[64][72];
  __shared__ __align__(16) unsigned short PH[64][72];
  __shared__ __align__(16) unsigned short PL[64][72];
  __shared__ float sacc[1024];
  for (int i2 = tid; i2 < 1024; i2 += 256) sacc[i2] = 0.f;

  int r0 = tid >> 3;                 // staging row 0..31
  int c8 = (tid & 7) * 8;            // staging col (u16)

  // K A-frags for this wave's 16 rows (A row = lane&15)
  int irow = it * 64 + w * 16 + c;
  short8 kfh[2], kfl[2];
#pragma unroll
  for (int ch = 0; ch < 2; ++ch) {
    kfh[ch] = *(const short8*)&kh[qb + (size_t)irow * 64 + ch * 32 + g * 8];
    kfl[ch] = *(const short8*)&kl[qb + (size_t)irow * 64 + ch * 32 + g * 8];
  }

  float m[4], lsum[4];
#pragma unroll
  for (int r = 0; r < 4; ++r) { m[r] = -3.0e38f; lsum[r] = 0.f; }

  // ---- pass 1: row max / denom (Q staged in LDS per jt) ----
  for (int jt = 0; jt < 16; ++jt) {
    __syncthreads();
#pragma unroll
    for (int rr = 0; rr < 2; ++rr) {
      int row = r0 + rr * 32;
      size_t go = qb + (size_t)(jt * 64 + row) * 64 + c8;
      *(short8*)&QH[row][c8] = *(const short8*)&qh[go];
      *(short8*)&QL[row][c8] = *(const short8*)&ql[go];
    }
    __syncthreads();
    f32x4 s[4];
#pragma unroll
    for (int su = 0; su < 4; ++su) s[su] = (f32x4){0.f, 0.f, 0.f, 0.f};
#pragma unroll
    for (int ch = 0; ch < 2; ++ch)
#pragma unroll
      for (int su = 0; su < 4; ++su) {
        short8 qfh = *(const short8*)&QH[su * 16 + c][ch * 32 + g * 8];
        short8 qfl = *(const short8*)&QL[su * 16 + c][ch * 32 + g * 8];
        s[su] = __builtin_amdgcn_mfma_f32_16x16x32_bf16(kfh[ch], qfh, s[su], 0, 0, 0);
        s[su] = __builtin_amdgcn_mfma_f32_16x16x32_bf16(kfl[ch], qfh, s[su], 0, 0, 0);
        s[su] = __builtin_amdgcn_mfma_f32_16x16x32_bf16(kfh[ch], qfl, s[su], 0, 0, 0);
      }
#pragma unroll
    for (int r = 0; r < 4; ++r) {
      float tm = fmaxf(fmaxf(s[0][r], s[1][r]), fmaxf(s[2][r], s[3][r]));
#pragma unroll
      for (int off = 1; off <= 8; off <<= 1) tm = fmaxf(tm, __shfl_xor(tm, off, 64));
      float mn = fmaxf(m[r], tm);
      float ts = ((expf(s[0][r] - mn) + expf(s[1][r] - mn)) +
                  expf(s[2][r] - mn)) + expf(s[3][r] - mn);
#pragma unroll
      for (int off = 1; off <= 8; off <<= 1) ts += __shfl_xor(ts, off, 64);
      lsum[r] = lsum[r] * expf(m[r] - mn) + ts;
      m[r] = mn;
    }
  }
  float inv[4];
#pragma unroll
  for (int r = 0; r < 4; ++r) inv[r] = 1.f / lsum[r];

  f32x4 oacc[4];
#pragma unroll
  for (int d = 0; d < 4; ++d) oacc[d] = (f32x4){0.f, 0.f, 0.f, 0.f};

  // ---- pass 2: P, scores, PV (Q+V staged in LDS per jt) ----
  for (int jt = 0; jt < 16; ++jt) {
    __syncthreads();
#pragma unroll
    for (int rr = 0; rr < 2; ++rr) {
      int row = r0 + rr * 32;
      size_t go = qb + (size_t)(jt * 64 + row) * 64 + c8;
      *(short8*)&QH[row][c8] = *(const short8*)&qh[go];
      *(short8*)&QL[row][c8] = *(const short8*)&ql[go];
      size_t vo = ((size_t)(bn * 64 + row)) * 1024 + jt * 64 + c8;
      *(short8*)&VH[row][c8] = *(const short8*)&vth[vo];
      *(short8*)&VL[row][c8] = *(const short8*)&vtl[vo];
    }
    __syncthreads();
    f32x4 s[4];
#pragma unroll
    for (int su = 0; su < 4; ++su) s[su] = (f32x4){0.f, 0.f, 0.f, 0.f};
#pragma unroll
    for (int ch = 0; ch < 2; ++ch)
#pragma unroll
      for (int su = 0; su < 4; ++su) {
        short8 qfh = *(const short8*)&QH[su * 16 + c][ch * 32 + g * 8];
        short8 qfl = *(const short8*)&QL[su * 16 + c][ch * 32 + g * 8];
        s[su] = __builtin_amdgcn_mfma_f32_16x16x32_bf16(kfh[ch], qfh, s[su], 0, 0, 0);
        s[su] = __builtin_amdgcn_mfma_f32_16x16x32_bf16(kfl[ch], qfh, s[su], 0, 0, 0);
        s[su] = __builtin_amdgcn_mfma_f32_16x16x32_bf16(kfh[ch], qfl, s[su], 0, 0, 0);
      }
#pragma unroll
    for (int su = 0; su < 4; ++su) {
      float p0 = expf(s[su][0] - m[0]) * inv[0];
      float p1 = expf(s[su][1] - m[1]) * inv[1];
      float p2 = expf(s[su][2] - m[2]) * inv[2];
      float p3 = expf(s[su][3] - m[3]) * inv[3];
      float cs = ((p0 + p1) + p2) + p3;
      cs += __shfl_xor(cs, 16, 64);
      cs += __shfl_xor(cs, 32, 64);
      if (g == 0) atomicAdd(&sacc[jt * 64 + su * 16 + c], cs);
      unsigned short h0 = f32_to_bf16_rne(p0);
      unsigned short h1 = f32_to_bf16_rne(p1);
      unsigned short h2 = f32_to_bf16_rne(p2);
      unsigned short h3 = f32_to_bf16_rne(p3);
      PH[w * 16 + g * 4 + 0][su * 16 + c] = h0;
      PH[w * 16 + g * 4 + 1][su * 16 + c] = h1;
      PH[w * 16 + g * 4 + 2][su * 16 + c] = h2;
      PH[w * 16 + g * 4 + 3][su * 16 + c] = h3;
      PL[w * 16 + g * 4 + 0][su * 16 + c] = f32_to_bf16_rne(p0 - bf16_to_f32(h0));
      PL[w * 16 + g * 4 + 1][su * 16 + c] = f32_to_bf16_rne(p1 - bf16_to_f32(h1));
      PL[w * 16 + g * 4 + 2][su * 16 + c] = f32_to_bf16_rne(p2 - bf16_to_f32(h2));
      PL[w * 16 + g * 4 + 3][su * 16 + c] = f32_to_bf16_rne(p3 - bf16_to_f32(h3));
    }
#pragma unroll
    for (int ch = 0; ch < 2; ++ch) {
      short8 pfh = *(const short8*)&PH[w * 16 + c][ch * 32 + g * 8];
      short8 pfl = *(const short8*)&PL[w * 16 + c][ch * 32 + g * 8];
#pragma unroll
      for (int d = 0; d < 4; ++d) {
        short8 vfh = *(const short8*)&VH[d * 16 + c][ch * 32 + g * 8];
        short8 vfl = *(const short8*)&VL[d * 16 + c][ch * 32 + g * 8];
        oacc[d] = __builtin_amdgcn_mfma_f32_16x16x32_bf16(vfh, pfh, oacc[d], 0, 0, 0);
        oacc[d] = __builtin_amdgcn_mfma_f32_16x16x32_bf16(vfl, pfh, oacc[d], 0, 0, 0);
        oacc[d] = __builtin_amdgcn_mfma_f32_16x16x32_bf16(vfh, pfl, oacc[d], 0, 0, 0);
      }
    }
  }
  // O natural [bn][i][d]: lane row i = it*64+w*16+c; cols d = dd*16+g*4+r
  {
    size_t obase = ((size_t)bn * 1024 + it * 64 + w * 16 + c) * 64;
#pragma unroll
    for (int dd = 0; dd < 4; ++dd) {
      short4v hh, ll;
#pragma unroll
      for (int r = 0; r < 4; ++r) {
        float v = oacc[dd][r];
        unsigned short h = f32_to_bf16_rne(v);
        hh[r] = (short)h;
        ll[r] = (short)f32_to_bf16_rne(v - bf16_to_f32(h));
      }
      *(short4v*)&atth[obase + dd * 16 + g * 4] = hh;
      *(short4v*)&attl[obase + dd * 16 + g * 4] = ll;
    }
  }
  __syncthreads();
  for (int i2 = tid; i2 < 1024; i2 += 256)
    spart[((size_t)bn * 16 + it) * 1024 + i2] = sacc[i2];
}

// ---------------- 4b. topk attention, split-bf16 MFMA (1-pass online) ----------
__global__ __launch_bounds__(256) void k_attn_online_mfma(
    const unsigned short* __restrict__ qh, const unsigned short* __restrict__ ql,
    const unsigned short* __restrict__ kh, const unsigned short* __restrict__ kl,
    const unsigned short* __restrict__ vth, const unsigned short* __restrict__ vtl,
    float* __restrict__ O) {
  int blk = blockIdx.x;
  int bn = blk & 31;                 // XCD-locality swizzle
  int it = blk >> 5;
  int tid = threadIdx.x;
  int w = tid >> 6;
  int lane = tid & 63;
  int g = lane >> 4;
  int c = lane & 15;
  size_t qb = (size_t)bn << 16;

  __shared__ __align__(16) unsigned short QH[64][72];
  __shared__ __align__(16) unsigned short QL[64][72];
  __shared__ __align__(16) unsigned short VH[64][72];
  __shared__ __align__(16) unsigned short VL[64][72];
  __shared__ __align__(16) unsigned short PH[64][72];
  __shared__ __align__(16) unsigned short PL[64][72];

  int r0 = tid >> 3;
  int c8 = (tid & 7) * 8;

  int irow = it * 64 + w * 16 + c;
  short8 kfh[2], kfl[2];
#pragma unroll
  for (int ch = 0; ch < 2; ++ch) {
    kfh[ch] = *(const short8*)&kh[qb + (size_t)irow * 64 + ch * 32 + g * 8];
    kfl[ch] = *(const short8*)&kl[qb + (size_t)irow * 64 + ch * 32 + g * 8];
  }

  float m[4], lsum[4];
  f32x4 oacc[4];
#pragma unroll
  for (int r = 0; r < 4; ++r) { m[r] = -3.0e38f; lsum[r] = 0.f; }
#pragma unroll
  for (int d = 0; d < 4; ++d) oacc[d] = (f32x4){0.f, 0.f, 0.f, 0.f};

  for (int jt = 0; jt < 16; ++jt) {
    __syncthreads();
#pragma unroll
    for (int rr = 0; rr < 2; ++rr) {
      int row = r0 + rr * 32;
      size_t go = qb + (size_t)(jt * 64 + row) * 64 + c8;
      *(short8*)&QH[row][c8] = *(const short8*)&qh[go];
      *(short8*)&QL[row][c8] = *(const short8*)&ql[go];
      size_t vo = ((size_t)(bn * 64 + row)) * 1024 + jt * 64 + c8;
      *(short8*)&VH[row][c8] = *(const short8*)&vth[vo];
      *(short8*)&VL[row][c8] = *(const short8*)&vtl[vo];
    }
    __syncthreads();
    f32x4 s[4];
#pragma unroll
    for (int su = 0; su < 4; ++su) s[su] = (f32x4){0.f, 0.f, 0.f, 0.f};
#pragma unroll
    for (int ch = 0; ch < 2; ++ch)
#pragma unroll
      for (int su = 0; su < 4; ++su) {
        short8 qfh = *(const short8*)&QH[su * 16 + c][ch * 32 + g * 8];
        short8 qfl = *(const short8*)&QL[su * 16 + c][ch * 32 + g * 8];
        s[su] = __builtin_amdgcn_mfma_f32_16x16x32_bf16(kfh[ch], qfh, s[su], 0, 0, 0);
        s[su] = __builtin_amdgcn_mfma_f32_16x16x32_bf16(kfl[ch], qfh, s[su], 0, 0, 0);
        s[su] = __builtin_amdgcn_mfma_f32_16x16x32_bf16(kfh[ch], qfl, s[su], 0, 0, 0);
      }
    float sc[4];
#pragma unroll
    for (int r = 0; r < 4; ++r) {
      float tm = fmaxf(fmaxf(s[0][r], s[1][r]), fmaxf(s[2][r], s[3][r]));
#pragma unroll
      for (int off = 1; off <= 8; off <<= 1) tm = fmaxf(tm, __shfl_xor(tm, off, 64));
      float mn = fmaxf(m[r], tm);
      sc[r] = expf(m[r] - mn);
      float p0 = expf(s[0][r] - mn);
      float p1 = expf(s[1][r] - mn);
      float p2 = expf(s[2][r] - mn);
      float p3 = expf(s[3][r] - mn);
      s[0][r] = p0; s[1][r] = p1; s[2][r] = p2; s[3][r] = p3;
      float ts = ((p0 + p1) + p2) + p3;
#pragma unroll
      for (int off = 1; off <= 8; off <<= 1) ts += __shfl_xor(ts, off, 64);
      lsum[r] = lsum[r] * sc[r] + ts;
      m[r] = mn;
    }
#pragma unroll
    for (int su = 0; su < 4; ++su) {
      unsigned short h0 = f32_to_bf16_rne(s[su][0]);
      unsigned short h1 = f32_to_bf16_rne(s[su][1]);
      unsigned short h2 = f32_to_bf16_rne(s[su][2]);
      unsigned short h3 = f32_to_bf16_rne(s[su][3]);
      PH[w * 16 + g * 4 + 0][su * 16 + c] = h0;
      PH[w * 16 + g * 4 + 1][su * 16 + c] = h1;
      PH[w * 16 + g * 4 + 2][su * 16 + c] = h2;
      PH[w * 16 + g * 4 + 3][su * 16 + c] = h3;
      PL[w * 16 + g * 4 + 0][su * 16 + c] = f32_to_bf16_rne(s[su][0] - bf16_to_f32(h0));
      PL[w * 16 + g * 4 + 1][su * 16 + c] = f32_to_bf16_rne(s[su][1] - bf16_to_f32(h1));
      PL[w * 16 + g * 4 + 2][su * 16 + c] = f32_to_bf16_rne(s[su][2] - bf16_to_f32(h2));
      PL[w * 16 + g * 4 + 3][su * 16 + c] = f32_to_bf16_rne(s[su][3] - bf16_to_f32(h3));
    }
    // rescale oacc by sc for col i=c (branchless select + shfl, rule #20 safe)
    float s01 = (c & 1) ? sc[1] : sc[0];
    float s23 = (c & 1) ? sc[3] : sc[2];
    float tmp = (c & 2) ? s23 : s01;
    float scc = __shfl(tmp, ((c >> 2) << 4) | c, 64);
#pragma unroll
    for (int d = 0; d < 4; ++d) oacc[d] *= scc;
#pragma unroll
    for (int ch = 0; ch < 2; ++ch) {
      short8 pfh = *(const short8*)&PH[w * 16 + c][ch * 32 + g * 8];
      short8 pfl = *(const short8*)&PL[w * 16 + c][ch * 32 + g * 8];
#pragma unroll
      for (int d = 0; d < 4; ++d) {
        short8 vfh = *(const short8*)&VH[d * 16 + c][ch * 32 + g * 8];
        short8 vfl = *(const short8*)&VL[d * 16 + c][ch * 32 + g * 8];
        oacc[d] = __builtin_amdgcn_mfma_f32_16x16x32_bf16(vfh, pfh, oacc[d], 0, 0, 0);
        oacc[d] = __builtin_amdgcn_mfma_f32_16x16x32_bf16(vfl, pfh, oacc[d], 0, 0, 0);
        oacc[d] = __builtin_amdgcn_mfma_f32_16x16x32_bf16(vfh, pfl, oacc[d], 0, 0, 0);
      }
    }
  }
  float i01 = (c & 1) ? (1.f / lsum[1]) : (1.f / lsum[0]);
  float i23 = (c & 1) ? (1.f / lsum[3]) : (1.f / lsum[2]);
  float itmp = (c & 2) ? i23 : i01;
  float invc = __shfl(itmp, ((c >> 2) << 4) | c, 64);
  // O natural [i][d]: lane col i = it*64+w*16+c; rows d = d*16+g*4+reg (contig f32x4)
#pragma unroll
  for (int d = 0; d < 4; ++d) {
    f32x4 o4 = oacc[d] * invc;
    *(f32x4*)&O[((size_t)bn * 1024 + it * 64 + w * 16 + c) * 64 + d * 16 + g * 4] = o4;
  }
}

// ---------------- 5. deterministic score reduction (16 partials) ----------------
__global__ __launch_bounds__(256) void k_score_reduce(const float* __restrict__ part,
                                                      float* __restrict__ score) {
  int j = blockIdx.x * 256 + threadIdx.x;   // 0..32767
  int bn = j >> 10, jj = j & 1023;
  float s = 0.f;
  for (int g = 0; g < 16; ++g) s += part[((size_t)bn * 16 + g) * 1024 + jj];
  score[j] = s;
}

// ---------------- 5b. default-init idx ----------------
__global__ __launch_bounds__(256) void k_idx_init(int* __restrict__ idx) {
  int j = blockIdx.x * 256 + threadIdx.x;
  idx[j] = j & 255;
}

// ---------------- 6. top-K by rank ----------------
__global__ __launch_bounds__(1024) void k_topk(const float* __restrict__ score,
                                               int* __restrict__ idxout) {
  int bn = blockIdx.x;
  int t = threadIdx.x;
  __shared__ float s[1024];
  s[t] = score[bn * 1024 + t];
  __syncthreads();
  float my = s[t];
  int rank = 0;
  for (int j = 0; j < 1024; ++j) {
    float o = s[j];
    rank += (o > my) || (o == my && j < t);
  }
  if (rank < 256) idxout[bn * 256 + rank] = t;
}

// ---------------- 7. transposed conv v7: v5 blocking + natural-layout staging --
// grid 512 = (b*2 + r)*32 + I; block: 1 oh row x ALL 256 co x both s (v5 proven).
// Staging from natural atth/attl [bn][i][d]: contiguous short8 loads +
// vectorized conflict-free LDS writes (the v6-validated staging, minus coh split).
__global__ __launch_bounds__(256) void k_conv_up_mfma(
    const unsigned short* __restrict__ atth, const unsigned short* __restrict__ attl,
    const unsigned short* __restrict__ whi, const unsigned short* __restrict__ wlo,
    const float* __restrict__ bias, float* __restrict__ cout,
    float* __restrict__ coutT) {
  int blk = blockIdx.x;              // (b*2 + r)*32 + I
  int I = blk & 31;
  int r = (blk >> 5) & 1;
  int b = blk >> 6;
  int tid = threadIdx.x;
  int w = tid >> 6;                  // wave -> co block w*64 (bn = b*4 + w)
  int lane = tid & 63;
  int lq = lane >> 4;
  int lr = lane & 15;

  __shared__ __align__(16) unsigned short AH[2][34][40];
  __shared__ __align__(16) unsigned short AL[2][34][40];

  f32x4 acc[2][2][4];                // [s][pfJ][cf]
#pragma unroll
  for (int s = 0; s < 2; ++s)
#pragma unroll
    for (int pf = 0; pf < 2; ++pf)
#pragma unroll
      for (int cf = 0; cf < 4; ++cf) acc[s][pf][cf] = (f32x4){0.f, 0.f, 0.f, 0.f};

  int ih0 = I + r - 1;
  const short8 zero8 = {0, 0, 0, 0, 0, 0, 0, 0};

  for (int ci0 = 0; ci0 < 256; ci0 += 32) {
    int n = ci0 >> 6, d0 = ci0 & 63;
    __syncthreads();
    // stage: 2 ih x 34 iw x 32 ci via contiguous short8 (272 vec loads)
    for (int idx = tid; idx < 272; idx += 256) {
      int q = idx & 3;
      int cell = idx >> 2;
      int rho = cell / 34;
      int col = cell - rho * 34;
      int ih = ih0 + rho;
      int iw = col - 1;
      short8 h = zero8, l = zero8;
      if ((unsigned)ih < 32u && (unsigned)iw < 32u) {
        size_t gg = ((size_t)((b * 4 + n) * 1024) + ih * 32 + iw) * 64 + d0 + q * 8;
        h = *(const short8*)&atth[gg];
        l = *(const short8*)&attl[gg];
      }
      *(short8*)&AH[rho][col][q * 8] = h;
      *(short8*)&AL[rho][col][q * 8] = l;
    }
    __syncthreads();
#pragma unroll
    for (int tap = 0; tap < 4; ++tap) {
      int a_ = tap >> 1, b_ = tap & 1;
      int rho = 1 - a_;
#pragma unroll
      for (int s = 0; s < 2; ++s) {
        int cls = r * 2 + s;
        size_t wb = (size_t)(cls * 4 + tap) * 65536;
        short8 bh[4], bl[4];
#pragma unroll
        for (int cf = 0; cf < 4; ++cf) {
          size_t off = wb + (size_t)(w * 64 + cf * 16 + lr) * 256 + ci0 + 8 * lq;
          bh[cf] = *(const short8*)&whi[off];
          bl[cf] = *(const short8*)&wlo[off];
        }
        short8 ah[2], al[2];
#pragma unroll
        for (int pf = 0; pf < 2; ++pf) {
          int col = pf * 16 + lr + s - b_ + 1;
          ah[pf] = *(const short8*)&AH[rho][col][8 * lq];
          al[pf] = *(const short8*)&AL[rho][col][8 * lq];
        }
#pragma unroll
        for (int pf = 0; pf < 2; ++pf)
#pragma unroll
          for (int cf = 0; cf < 4; ++cf) {
            acc[s][pf][cf] = __builtin_amdgcn_mfma_f32_16x16x32_bf16(ah[pf], bh[cf], acc[s][pf][cf], 0, 0, 0);
            acc[s][pf][cf] = __builtin_amdgcn_mfma_f32_16x16x32_bf16(al[pf], bh[cf], acc[s][pf][cf], 0, 0, 0);
            acc[s][pf][cf] = __builtin_amdgcn_mfma_f32_16x16x32_bf16(ah[pf], bl[cf], acc[s][pf][cf], 0, 0, 0);
          }
      }
    }
  }

  int oh = 2 * I + r;
#pragma unroll
  for (int cf = 0; cf < 4; ++cf) {
    int co = w * 64 + cf * 16 + lr;
    float bv = bias[co];
    size_t cbase = ((size_t)b * 256 + co) * 4096 + (size_t)oh * 64;
    size_t tbase = (((size_t)(b * 4 + w) * 4096) + oh * 64) * 64 + (co & 63);
#pragma unroll
    for (int pf = 0; pf < 2; ++pf)
#pragma unroll
      for (int reg = 0; reg < 4; ++reg) {
        int J = pf * 16 + lq * 4 + reg;
        float v0 = acc[0][pf][cf][reg] + bv;
        float v1 = acc[1][pf][cf][reg] + bv;
        *(float2*)&cout[cbase + 2 * J] = make_float2(v0, v1);
        coutT[tbase + (size_t)(2 * J) * 64] = v0;
        coutT[tbase + (size_t)(2 * J + 1) * 64] = v1;
      }
  }
}

// ---------------- 8. y = coarse_out + region ----------------
__global__ __launch_bounds__(256) void k_ybuild(const float* __restrict__ cout,
                                                float* __restrict__ y) {
  size_t e = (size_t)blockIdx.x * 256 + threadIdx.x;
  int flat = (int)(e & 4095);
  size_t bc = e >> 12;
  int p = flat >> 2, ab = flat & 3;
  int a = ab >> 1, bi = ab & 1;
  int src = ((p >> 5) * 2 + a) * 64 + (p & 31) * 2 + bi;
  const float* cb = cout + bc * 4096;
  y[e] = cb[flat] + cb[src];
}

// ---------------- 9. scatter-add attended tokens ----------------
__global__ __launch_bounds__(256) void k_scatter(const float* __restrict__ out2,
    const int* __restrict__ idx, float* __restrict__ y) {
  int e = blockIdx.x * 256 + threadIdx.x;
  int d = e & 63;
  int r = e >> 6;
  int ab = r & 3;
  int r2 = r >> 2;
  int kk = r2 & 255;
  int bn = r2 >> 8;
  int b = bn >> 2, n = bn & 3;
  int p = idx[bn * 256 + kk] & 1023;
  int flat = p * 4 + ab;
  int t = kk * 4 + ab;
  y[((size_t)(b * 256 + n * 64 + d)) * 4096 + flat] +=
      out2[((size_t)bn * 1024 + t) * 64 + d];
}

// ---------------- 10. depthwise 3x3 + BN + relu6 ----------------
__global__ __launch_bounds__(256) void k_dw(const float* __restrict__ y,
    const float* __restrict__ w, const float* __restrict__ g, const float* __restrict__ bb,
    const float* __restrict__ mm, const float* __restrict__ vv, float* __restrict__ t1) {
  size_t e = (size_t)blockIdx.x * 256 + threadIdx.x;
  int pix = (int)(e & 4095);
  int c = (int)((e >> 12) & 255);
  int oh = pix >> 6, ow = pix & 63;
  const float* yb = y + (e - pix);
  float acc = 0.f;
#pragma unroll
  for (int kh = 0; kh < 3; ++kh) {
    int ih = oh - 1 + kh;
    if ((unsigned)ih >= 64u) continue;
#pragma unroll
    for (int kw = 0; kw < 3; ++kw) {
      int iw = ow - 1 + kw;
      if ((unsigned)iw >= 64u) continue;
      acc = fmaf(yb[ih * 64 + iw], w[c * 9 + kh * 3 + kw], acc);
    }
  }
  float s = g[c] * rsqrtf(vv[c] + 1e-5f);
  float val = acc * s + (bb[c] - mm[c] * s);
  t1[e] = fminf(fmaxf(val, 0.f), 6.f);
}

// ---------------- 11. pointwise v2: 4 co per block, 16 FMA per 16B load --------
__global__ __launch_bounds__(256) void k_pw2(const float* __restrict__ t1,
    const float* __restrict__ w, const float* __restrict__ g, const float* __restrict__ bb,
    const float* __restrict__ mm, const float* __restrict__ vv, float* __restrict__ out) {
  int blk = blockIdx.x;              // (b*64 + cog)*4 + tile
  int tile = blk & 3;
  int cog = (blk >> 2) & 63;
  int b = blk >> 8;
  int co0 = cog * 4;
  int t = threadIdx.x;
  __shared__ float wl[256][4];
  for (int idx = t; idx < 1024; idx += 256) {
    int cof = idx >> 8;
    int ci = idx & 255;
    wl[ci][cof] = w[(co0 + cof) * 256 + ci];
  }
  __syncthreads();
  int px0 = tile * 1024 + t * 4;
  const float* tb = t1 + (size_t)b * 256 * 4096 + px0;
  float acc[4][4];
#pragma unroll
  for (int a = 0; a < 4; ++a)
#pragma unroll
    for (int jj = 0; jj < 4; ++jj) acc[a][jj] = 0.f;
  for (int ci = 0; ci < 256; ++ci) {
    float4 tv = *(const float4*)(tb + (size_t)ci * 4096);
    float4 wv = *(const float4*)&wl[ci][0];
    acc[0][0] = fmaf(tv.x, wv.x, acc[0][0]); acc[0][1] = fmaf(tv.y, wv.x, acc[0][1]);
    acc[0][2] = fmaf(tv.z, wv.x, acc[0][2]); acc[0][3] = fmaf(tv.w, wv.x, acc[0][3]);
    acc[1][0] = fmaf(tv.x, wv.y, acc[1][0]); acc[1][1] = fmaf(tv.y, wv.y, acc[1][1]);
    acc[1][2] = fmaf(tv.z, wv.y, acc[1][2]); acc[1][3] = fmaf(tv.w, wv.y, acc[1][3]);
    acc[2][0] = fmaf(tv.x, wv.z, acc[2][0]); acc[2][1] = fmaf(tv.y, wv.z, acc[2][1]);
    acc[2][2] = fmaf(tv.z, wv.z, acc[2][2]); acc[2][3] = fmaf(tv.w, wv.z, acc[2][3]);
    acc[3][0] = fmaf(tv.x, wv.w, acc[3][0]); acc[3][1] = fmaf(tv.y, wv.w, acc[3][1]);
    acc[3][2] = fmaf(tv.z, wv.w, acc[3][2]); acc[3][3] = fmaf(tv.w, wv.w, acc[3][3]);
  }
#pragma unroll
  for (int a = 0; a < 4; ++a) {
    int co = co0 + a;
    float s = g[co] * rsqrtf(vv[co] + 1e-5f);
    float bias = bb[co] - mm[co] * s;
    float4 o4;
    o4.x = fminf(fmaxf(acc[a][0] * s + bias, 0.f), 6.f);
    o4.y = fminf(fmaxf(acc[a][1] * s + bias, 0.f), 6.f);
    o4.z = fminf(fmaxf(acc[a][2] * s + bias, 0.f), 6.f);
    o4.w = fminf(fmaxf(acc[a][3] * s + bias, 0.f), 6.f);
    *(float4*)(out + ((size_t)(b * 256 + co)) * 4096 + px0) = o4;
  }
}

// ---------------- launcher ----------------
extern "C" void kernel_launch(void* const* d_in, const int* in_sizes, int n_in,
                              void* d_out, int out_size, void* d_ws, size_t ws_size,
                              hipStream_t stream) {
  if (ws_size < WS_FLOATS * sizeof(float)) return;

  const float* x      = (const float*)d_in[0];
  const float* down_w = (const float*)d_in[1];
  const float* down_b = (const float*)d_in[2];
  const float* up_w   = (const float*)d_in[3];
  const float* up_b   = (const float*)d_in[4];
  const float* cqkv_w = (const float*)d_in[5];
  const float* cqkv_b = (const float*)d_in[6];
  const float* tqkv_w = (const float*)d_in[7];
  const float* tqkv_b = (const float*)d_in[8];
  const float* dww    = (const float*)d_in[9];
  const float* bn1g   = (const float*)d_in[10];
  const float* bn1b   = (const float*)d_in[11];
  const float* bn1m   = (const float*)d_in[12];
  const float* bn1v   = (const float*)d_in[13];
  const float* pww    = (const float*)d_in[14];
  const float* bn2g   = (const float*)d_in[15];
  const float* bn2b   = (const float*)d_in[16];
  const float* bn2m   = (const float*)d_in[17];
  const float* bn2v   = (const float*)d_in[18];

  float* ws    = (float*)d_ws;
  float* att   = ws + OFF_ATT;
  float* spart = ws + OFF_SPART;
  float* score = ws + OFF_SCORE;
  int*   idx   = (int*)(ws + OFF_IDX);
  float* cout  = ws + OFF_COUT;
  float* y     = ws + OFF_Y;
  float* t1    = ws + OFF_T1;
  unsigned short* atth = (unsigned short*)(ws + OFF_SPART + 2097152);  // O natural hi (2M u16)
  unsigned short* attl = (unsigned short*)(ws + OFF_SPART + 3145728);  // O natural lo (2M u16)
  unsigned short* whi  = (unsigned short*)(ws + OFF_XD);            // up-w hi
  unsigned short* wlo  = (unsigned short*)(ws + OFF_XD + 524288);   // up-w lo
  unsigned short* dwhi = (unsigned short*)(ws + OFF_SPART);             // down-w hi (dead after conv_down)
  unsigned short* dwlo = (unsigned short*)(ws + OFF_SPART + 524288);    // down-w lo
  unsigned short* xbh  = (unsigned short*)(ws + OFF_Q);   // x hi (Q..K regions, dead after conv_down)
  unsigned short* xbl  = (unsigned short*)(ws + OFF_V);   // x lo (V..ATT regions, dead after conv_down)
  unsigned short* qh   = (unsigned short*)(ws + OFF_Q);
  unsigned short* ql   = (unsigned short*)(ws + OFF_Q + 1048576);
  unsigned short* kh   = (unsigned short*)(ws + OFF_K);
  unsigned short* kl   = (unsigned short*)(ws + OFF_K + 1048576);
  unsigned short* vth  = (unsigned short*)(ws + OFF_V);
  unsigned short* vtl  = (unsigned short*)(ws + OFF_V + 1048576);
  float* coutT = ws + OFF_T1;                // t1 region dead until k_dw
  float* dpart = ws + OFF_Y;                 // 4 x 2M ci-split partials (dead until k_ybuild)

  k_x2bf<<<1024, 256, 0, stream>>>(x, xbh, xbl);
  k_wt_dnb<<<4096, 256, 0, stream>>>(down_w, dwhi, dwlo);
  k_conv_down_mfma<<<4096, 256, 0, stream>>>(xbh, xbl, dwhi, dwlo, down_b, dpart);
  k_qkv_coarse<<<512, 192, 0, stream>>>(dpart, cqkv_w, cqkv_b, qh, ql, kh, kl, vth, vtl);
  k_wt_upb<<<4096, 256, 0, stream>>>(up_w, whi, wlo);
  k_attn_score_mfma<<<512, 256, 0, stream>>>(qh, ql, kh, kl, vth, vtl, spart, atth, attl);
  k_score_reduce<<<128, 256, 0, stream>>>(spart, score);
  k_idx_init<<<32, 256, 0, stream>>>(idx);
  k_topk<<<32, 1024, 0, stream>>>(score, idx);
  k_conv_up_mfma<<<512, 256, 0, stream>>>(atth, attl, whi, wlo, up_b, cout, coutT);
  k_qkv_topk<<<512, 192, 0, stream>>>(coutT, idx, tqkv_w, tqkv_b, qh, ql, kh, kl, vth, vtl);
  k_attn_online_mfma<<<512, 256, 0, stream>>>(qh, ql, kh, kl, vth, vtl, att);
  k_ybuild<<<32768, 256, 0, stream>>>(cout, y);
  k_scatter<<<8192, 256, 0, stream>>>(att, idx, y);
  k_dw<<<32768, 256, 0, stream>>>(y, dww, bn1g, bn1b, bn1m, bn1v, t1);
  k_pw2<<<2048, 256, 0, stream>>>(t1, pww, bn2g, bn2b, bn2m, bn2v, (float*)d_out);
}